// Round 1
// baseline (622.571 us; speedup 1.0000x reference)
//
#include <hip/hip_runtime.h>

#define NN 10000      // nodes
#define NE 160000     // edges
#define NGB 100       // graphs

static __device__ __forceinline__ float lrelu(float v){ return v > 0.f ? v : 0.2f*v; }

// ---------------- CSR build ----------------
__global__ __launch_bounds__(256) void k_degrees(const int* __restrict__ src, const int* __restrict__ dst,
                                                 int* deg_src, int* deg_dst){
  int i = blockIdx.x*256 + threadIdx.x;
  if (i < NE){ atomicAdd(&deg_src[src[i]],1); atomicAdd(&deg_dst[dst[i]],1); }
}

__global__ __launch_bounds__(1024) void k_scan(const int* __restrict__ deg_src, const int* __restrict__ deg_dst,
                                               int* rp_src, int* rp_dst){
  const int* deg = (blockIdx.x==0) ? deg_src : deg_dst;
  int* rp = (blockIdx.x==0) ? rp_src : rp_dst;
  __shared__ int part[1024];
  int tid = threadIdx.x;
  const int per = (NN + 1023)/1024;   // 10
  int base = tid*per;
  int s = 0;
  for (int i=0;i<per;i++){ int idx=base+i; if (idx<NN) s += deg[idx]; }
  part[tid]=s; __syncthreads();
  for (int off=1; off<1024; off<<=1){
    int v = part[tid];
    int add = (tid>=off) ? part[tid-off] : 0;
    __syncthreads();
    part[tid] = v + add;
    __syncthreads();
  }
  int run = (tid==0) ? 0 : part[tid-1];
  for (int i=0;i<per;i++){ int idx=base+i; if (idx<NN){ rp[idx]=run; run += deg[idx]; } }
  if (tid==1023) rp[NN] = part[1023];
}

__global__ __launch_bounds__(256) void k_fill(const int* __restrict__ src, const int* __restrict__ dst,
                       const int* __restrict__ rp_src, const int* __restrict__ rp_dst,
                       int* fill_src, int* fill_dst, int* eid_src, int* eid_dst){
  int i = blockIdx.x*256 + threadIdx.x;
  if (i < NE){
    int s=src[i]; int p=rp_src[s]+atomicAdd(&fill_src[s],1); eid_src[p]=i;
    int d=dst[i]; int q=rp_dst[d]+atomicAdd(&fill_dst[d],1); eid_dst[q]=i;
  }
}

// graph boundaries from sorted batch (handles empty graphs)
__global__ __launch_bounds__(256) void k_bounds(const int* __restrict__ batch, int* starts){
  int n = blockIdx.x*256 + threadIdx.x;
  if (n > NN) return;
  int cur  = (n==NN) ? NGB : batch[n];
  int prev = (n==0)  ? -1  : batch[n-1];
  for (int b=prev+1; b<=cur; b++) if (b<=NGB) starts[b]=n;
}

// ---------------- EdgeMLP layers 1+2 fused: t2[E,64] ----------------
// 4 waves/block, 4 edges/wave (amortizes We2 LDS reads 4x)
__global__ __launch_bounds__(256) void k_edge_mlp(const float* __restrict__ ea,
    const float* __restrict__ We1, const float* __restrict__ be1,
    const float* __restrict__ We2, const float* __restrict__ be2,
    float* __restrict__ t2){
  __shared__ float sW1[16*128];
  __shared__ float sW2[128*64];
  __shared__ float sb1[128];
  __shared__ float sb2[64];
  __shared__ float st1[16][128];
  int tid = threadIdx.x;
  for (int i=tid;i<16*128;i+=256) sW1[i]=We1[i];
  for (int i=tid;i<128*64;i+=256) sW2[i]=We2[i];
  if (tid<128) sb1[tid]=be1[tid];
  if (tid<64)  sb2[tid]=be2[tid];
  __syncthreads();
  int wave=tid>>6, lane=tid&63;
  for (int eb = blockIdx.x*16; eb < NE; eb += gridDim.x*16){   // NE % 16 == 0
    int e0 = eb + wave*4;
    #pragma unroll
    for (int q=0;q<4;q++){
      int e = e0 + q;
      const float* a = ea + (size_t)e*16;
      float4 a0 = *reinterpret_cast<const float4*>(a);
      float4 a1 = *reinterpret_cast<const float4*>(a+4);
      float4 a2 = *reinterpret_cast<const float4*>(a+8);
      float4 a3 = *reinterpret_cast<const float4*>(a+12);
      float r[16] = {a0.x,a0.y,a0.z,a0.w,a1.x,a1.y,a1.z,a1.w,
                     a2.x,a2.y,a2.z,a2.w,a3.x,a3.y,a3.z,a3.w};
      float acc0=sb1[lane], acc1=sb1[lane+64];
      #pragma unroll
      for (int i=0;i<16;i++){
        acc0 += r[i]*sW1[i*128+lane];
        acc1 += r[i]*sW1[i*128+lane+64];
      }
      st1[wave*4+q][lane]    = fmaxf(acc0,0.f);
      st1[wave*4+q][lane+64] = fmaxf(acc1,0.f);
    }
    __syncthreads();
    float acc[4] = {sb2[lane],sb2[lane],sb2[lane],sb2[lane]};
    #pragma unroll
    for (int k4=0;k4<32;k4++){
      float w0=sW2[(k4*4+0)*64+lane];
      float w1=sW2[(k4*4+1)*64+lane];
      float w2=sW2[(k4*4+2)*64+lane];
      float w3=sW2[(k4*4+3)*64+lane];
      #pragma unroll
      for (int q=0;q<4;q++){
        float4 tv = *reinterpret_cast<const float4*>(&st1[wave*4+q][k4*4]);
        acc[q] += tv.x*w0 + tv.y*w1 + tv.z*w2 + tv.w*w3;
      }
    }
    #pragma unroll
    for (int q=0;q<4;q++) t2[(size_t)(e0+q)*64+lane] = fmaxf(acc[q],0.f);
    __syncthreads();
  }
}

// ---------------- Y[n, k*32+o] = sum_f x[n,f]*We3[k, f*32+o]; xb[n,o] = sum_f x[n,f]*be3[f*32+o] ----------------
__global__ __launch_bounds__(256) void k_y(const float* __restrict__ x,
    const float* __restrict__ We3, const float* __restrict__ be3,
    float* __restrict__ Y, float* __restrict__ xb){
  int jb = blockIdx.x & 7;
  int cb = blockIdx.x >> 3;
  int nchunks = gridDim.x >> 3;
  int j = jb*256 + threadIdx.x;   // 0..2047
  int k = j >> 5, o = j & 31;
  float w[32];
  #pragma unroll
  for (int f=0;f<32;f++) w[f] = We3[k*1024 + f*32 + o];
  int per = (NN + nchunks - 1)/nchunks;
  int n0 = cb*per;
  int n1 = min(n0+per, NN);
  for (int n=n0;n<n1;n++){
    const float* xr = x + (size_t)n*32;
    float acc = 0.f;
    #pragma unroll
    for (int f=0;f<32;f++) acc += xr[f]*w[f];
    Y[(size_t)n*2048 + j] = acc;
  }
  if (jb == 0){
    int oo = threadIdx.x & 31;
    int sub = threadIdx.x >> 5;
    float wb[32];
    #pragma unroll
    for (int f=0;f<32;f++) wb[f] = be3[f*32+oo];
    for (int n=n0+sub;n<n1;n+=8){
      const float* xr = x + (size_t)n*32;
      float acc = 0.f;
      #pragma unroll
      for (int f=0;f<32;f++) acc += xr[f]*wb[f];
      xb[(size_t)n*32+oo] = acc;
    }
  }
}

// ---------------- msg[e,o] = xb[src,o] + sum_k t2[e,k]*Y[src, k*32+o]  (CSR by src: Y row staged once) ----------------
__global__ __launch_bounds__(256) void k_msg(const float* __restrict__ Y,
    const float* __restrict__ xb, const float* __restrict__ t2,
    const int* __restrict__ rp_src, const int* __restrict__ eid_src,
    float* __restrict__ msg){
  __shared__ float Ys[2048];
  __shared__ float t2s[8][64];
  __shared__ float xbs[32];
  for (int n = blockIdx.x; n < NN; n += gridDim.x){
    int beg = rp_src[n], end = rp_src[n+1];
    int deg = end - beg;
    if (deg == 0) continue;                       // uniform per block
    for (int i=threadIdx.x;i<2048;i+=256) Ys[i] = Y[(size_t)n*2048+i];
    if (threadIdx.x < 32) xbs[threadIdx.x] = xb[(size_t)n*32+threadIdx.x];
    __syncthreads();
    int o = threadIdx.x & 31;
    int slot = threadIdx.x >> 5;                  // 0..7
    for (int base=0; base<deg; base+=8){
      int nb = min(8, deg-base);
      for (int i=threadIdx.x; i<nb*64; i+=256){
        int sl = i>>6, kk = i&63;
        int e = eid_src[beg+base+sl];
        t2s[sl][kk] = t2[(size_t)e*64+kk];
      }
      __syncthreads();
      if (slot < nb){
        int e = eid_src[beg+base+slot];
        float acc = xbs[o];
        #pragma unroll
        for (int k4=0;k4<16;k4++){
          float4 tv = *reinterpret_cast<const float4*>(&t2s[slot][k4*4]);
          acc += tv.x*Ys[(k4*4+0)*32+o];
          acc += tv.y*Ys[(k4*4+1)*32+o];
          acc += tv.z*Ys[(k4*4+2)*32+o];
          acc += tv.w*Ys[(k4*4+3)*32+o];
        }
        msg[(size_t)e*32+o] = acc;
      }
      __syncthreads();
    }
  }
}

// ---------------- h0raw = segsum(msg by dst) + x@Wroot + bc1 ----------------
__global__ __launch_bounds__(256) void k_conv(const float* __restrict__ msg,
    const float* __restrict__ x, const float* __restrict__ Wroot, const float* __restrict__ bc1,
    const int* __restrict__ rp_dst, const int* __restrict__ eid_dst,
    float* __restrict__ h0raw){
  __shared__ float sW[32*32];
  __shared__ float sb[32];
  int tid = threadIdx.x;
  for (int i=tid;i<1024;i+=256) sW[i]=Wroot[i];
  if (tid<32) sb[tid]=bc1[tid];
  __syncthreads();
  int wave=tid>>6, lane=tid&63;
  int f=lane&31, half=lane>>5;
  for (int n = blockIdx.x*4+wave; n < NN; n += gridDim.x*4){
    int beg=rp_dst[n], end=rp_dst[n+1];
    float acc=0.f;
    for (int i=beg+half;i<end;i+=2){
      int e = eid_dst[i];
      acc += msg[(size_t)e*32+f];
    }
    acc += __shfl_xor(acc,32);
    if (half==0){
      const float* xr = x + (size_t)n*32;
      float r = sb[f];
      #pragma unroll
      for (int k=0;k<32;k++) r += xr[k]*sW[k*32+f];
      h0raw[(size_t)n*32+f] = acc + r;
    }
  }
}

// ---------------- column stats (sum, sumsq) for BN; stats must be pre-zeroed ----------------
__global__ __launch_bounds__(256) void k_stats(const float* __restrict__ buf, int nrows, int ncols,
                                               float* __restrict__ stats){
  int tid = threadIdx.x;
  int c  = tid % ncols;
  int r0 = tid / ncols;
  int rp = 256 / ncols;
  float s1=0.f, s2=0.f;
  for (long long base=(long long)blockIdx.x*rp; base<nrows; base+=(long long)gridDim.x*rp){
    int r = (int)base + r0;
    if (r < nrows){
      float v = buf[(size_t)r*ncols + c];
      s1 += v; s2 += v*v;
    }
  }
  __shared__ float A[256], B[256];
  A[tid]=s1; B[tid]=s2; __syncthreads();
  if (tid < ncols){
    float t1=0.f, t2=0.f;
    for (int gg=0; gg<256/ncols; gg++){ t1 += A[gg*ncols+tid]; t2 += B[gg*ncols+tid]; }
    atomicAdd(&stats[tid], t1);
    atomicAdd(&stats[ncols+tid], t2);
  }
}

// ---------------- GAT linear: in = relu(bn(raw)); hW = in@W; sc_s = hW@a_s; sc_d = hW@a_d ----------------
template<int FIN, int FOUT>
__global__ __launch_bounds__(256) void k_gat_linear(const float* __restrict__ raw,
    const float* __restrict__ stats, const float* __restrict__ W,
    const float* __restrict__ avs, const float* __restrict__ avd,
    float* __restrict__ hW, float* __restrict__ sc_s, float* __restrict__ sc_d){
  __shared__ float sW[FIN*FOUT];
  __shared__ float sA[FOUT], sD[FOUT];
  __shared__ float sScale[FIN], sShift[FIN];
  __shared__ float sIn[4][FIN];
  int tid = threadIdx.x;
  for (int i=tid;i<FIN*FOUT;i+=256) sW[i]=W[i];
  if (tid<FOUT){ sA[tid]=avs[tid]; sD[tid]=avd[tid]; }
  if (tid<FIN){
    float m = stats[tid]*(1.f/NN);
    float v = stats[FIN+tid]*(1.f/NN) - m*m;
    float s = rsqrtf(v + 1e-5f);
    sScale[tid]=s; sShift[tid]=-m*s;
  }
  __syncthreads();
  int wave=tid>>6, lane=tid&63;
  for (int nb = blockIdx.x*4; nb < NN; nb += gridDim.x*4){
    int n = nb + wave;
    bool act = n < NN;
    if (act){
      for (int ff=lane; ff<FIN; ff+=64){
        float vv = raw[(size_t)n*FIN+ff]*sScale[ff]+sShift[ff];
        sIn[wave][ff] = fmaxf(vv, 0.f);
      }
    }
    __syncthreads();
    if (act){
      float out0=0.f, out1=0.f;
      #pragma unroll
      for (int ff=0; ff<FIN; ff++){
        float xv = sIn[wave][ff];
        out0 += xv*sW[ff*FOUT+lane];
        if constexpr (FOUT > 64) out1 += xv*sW[ff*FOUT+lane+64];
      }
      hW[(size_t)n*FOUT+lane] = out0;
      float ps = out0*sA[lane], pd = out0*sD[lane];
      if constexpr (FOUT > 64){
        hW[(size_t)n*FOUT+lane+64] = out1;
        ps += out1*sA[lane+64]; pd += out1*sD[lane+64];
      }
      #pragma unroll
      for (int off=32;off>0;off>>=1){ ps += __shfl_down(ps,off); pd += __shfl_down(pd,off); }
      if (lane==0){ sc_s[n]=ps; sc_d[n]=pd; }
    }
    __syncthreads();
  }
}

// ---------------- GAT attention + aggregate (segment softmax over in-edges + self loop) ----------------
template<int F>
__global__ __launch_bounds__(256) void k_gat_attn(const float* __restrict__ hW,
    const float* __restrict__ sc_s, const float* __restrict__ sc_d,
    const int* __restrict__ rp_dst, const int* __restrict__ eid_dst,
    const int* __restrict__ src, const float* __restrict__ bias,
    float* __restrict__ outraw){
  int tid=threadIdx.x;
  int wave=tid>>6, lane=tid&63;
  for (int n = blockIdx.x*4+wave; n < NN; n += gridDim.x*4){
    int beg=rp_dst[n], end=rp_dst[n+1];
    float scd = sc_d[n];
    float sself = lrelu(sc_s[n]+scd);
    float m = sself;
    for (int i=beg+lane;i<end;i+=64){
      int e=eid_dst[i];
      m = fmaxf(m, lrelu(sc_s[src[e]]+scd));
    }
    #pragma unroll
    for (int off=32;off>0;off>>=1) m = fmaxf(m, __shfl_xor(m,off));
    float ssum = 0.f;
    for (int i=beg+lane;i<end;i+=64){
      int e=eid_dst[i];
      ssum += expf(lrelu(sc_s[src[e]]+scd)-m);
    }
    #pragma unroll
    for (int off=32;off>0;off>>=1) ssum += __shfl_xor(ssum,off);
    float pself = expf(sself-m);
    float inv = 1.f/(ssum + pself + 1e-16f);
    float acc0=0.f, acc1=0.f;
    for (int i=beg;i<end;i++){
      int e=eid_dst[i];
      int s=src[e];
      float p = expf(lrelu(sc_s[s]+scd)-m);
      acc0 += p*hW[(size_t)s*F+lane];
      if constexpr (F > 64) acc1 += p*hW[(size_t)s*F+lane+64];
    }
    acc0 += pself*hW[(size_t)n*F+lane];
    outraw[(size_t)n*F+lane] = acc0*inv + bias[lane];
    if constexpr (F > 64){
      acc1 += pself*hW[(size_t)n*F+lane+64];
      outraw[(size_t)n*F+lane+64] = acc1*inv + bias[lane+64];
    }
  }
}

// ---------------- mean pool with bn+relu on read ----------------
__global__ __launch_bounds__(256) void k_pool(const float* __restrict__ h2raw,
    const float* __restrict__ stats, const int* __restrict__ starts,
    float* __restrict__ g){
  __shared__ float sc[128], sh[128];
  __shared__ float red[256];
  int b=blockIdx.x, t=threadIdx.x;
  if (t<128){
    float m = stats[t]*(1.f/NN);
    float v = stats[128+t]*(1.f/NN) - m*m;
    float s = rsqrtf(v+1e-5f);
    sc[t]=s; sh[t]=-m*s;
  }
  __syncthreads();
  int s0=starts[b], s1=starts[b+1];
  int f=t&127, half=t>>7;
  float acc=0.f;
  for (int n=s0+half;n<s1;n+=2){
    float v = h2raw[(size_t)n*128+f]*sc[f]+sh[f];
    acc += fmaxf(v,0.f);
  }
  red[t]=acc; __syncthreads();
  if (half==0){
    int cnt = s1-s0;
    g[b*128+f] = (red[f]+red[128+f]) / fmaxf((float)cnt, 1.f);
  }
}

// ---------------- FC head ----------------
__global__ __launch_bounds__(256) void k_head1(const float* __restrict__ g,
    const float* __restrict__ Wf1, const float* __restrict__ bf1, float* __restrict__ g1){
  __shared__ float sg[128];
  int r=blockIdx.x, t=threadIdx.x;
  if (t<128) sg[t]=g[r*128+t];
  __syncthreads();
  float acc=bf1[t];
  #pragma unroll 4
  for (int k=0;k<128;k++) acc += sg[k]*Wf1[k*256+t];
  g1[r*256+t]=acc;
}

__global__ __launch_bounds__(256) void k_head2(const float* __restrict__ g1,
    const float* __restrict__ stats, const float* __restrict__ Wf2,
    const float* __restrict__ bf2, float* __restrict__ g2){
  __shared__ float sin_[256];
  int r=blockIdx.x, t=threadIdx.x;
  float m = stats[t]*(1.f/NGB);
  float v = stats[256+t]*(1.f/NGB) - m*m;
  float val = (g1[r*256+t]-m)*rsqrtf(v+1e-5f);
  sin_[t]=fmaxf(val,0.f);
  __syncthreads();
  if (t<128){
    float acc=bf2[t];
    #pragma unroll 4
    for (int k=0;k<256;k++) acc += sin_[k]*Wf2[k*128+t];
    g2[r*128+t]=acc;
  }
}

__global__ __launch_bounds__(256) void k_head3(const float* __restrict__ g2,
    const float* __restrict__ stats, const float* __restrict__ Wf3,
    const float* __restrict__ bf3, float* __restrict__ out){
  __shared__ float sin_[128];
  int r=blockIdx.x, t=threadIdx.x;
  if (t<128){
    float m = stats[t]*(1.f/NGB);
    float v = stats[128+t]*(1.f/NGB) - m*m;
    float val = (g2[r*128+t]-m)*rsqrtf(v+1e-5f);
    sin_[t]=fmaxf(val,0.f);
  }
  __syncthreads();
  if (t<64){
    float acc=bf3[t];
    #pragma unroll 4
    for (int k=0;k<128;k++) acc += sin_[k]*Wf3[k*64+t];
    out[r*64+t]=acc;
  }
}

extern "C" void kernel_launch(void* const* d_in, const int* in_sizes, int n_in,
                              void* d_out, int out_size, void* d_ws, size_t ws_size,
                              hipStream_t stream){
  const float* x    = (const float*)d_in[0];
  const int*   ei   = (const int*)d_in[1];
  const float* ea   = (const float*)d_in[2];
  const int*   batch= (const int*)d_in[3];
  const float* We1=(const float*)d_in[4];  const float* be1=(const float*)d_in[5];
  const float* We2=(const float*)d_in[6];  const float* be2=(const float*)d_in[7];
  const float* We3=(const float*)d_in[8];  const float* be3=(const float*)d_in[9];
  const float* Wroot=(const float*)d_in[10]; const float* bc1=(const float*)d_in[11];
  const float* Wg1=(const float*)d_in[12]; const float* as1=(const float*)d_in[13];
  const float* ad1=(const float*)d_in[14]; const float* bg1=(const float*)d_in[15];
  const float* Wg2=(const float*)d_in[16]; const float* as2=(const float*)d_in[17];
  const float* ad2=(const float*)d_in[18]; const float* bg2=(const float*)d_in[19];
  const float* Wf1=(const float*)d_in[20]; const float* bf1=(const float*)d_in[21];
  const float* Wf2=(const float*)d_in[22]; const float* bf2=(const float*)d_in[23];
  const float* Wf3=(const float*)d_in[24]; const float* bf3=(const float*)d_in[25];
  (void)in_sizes; (void)n_in; (void)out_size; (void)ws_size;
  float* out = (float*)d_out;
  char* ws = (char*)d_ws;
  const int* srcA = ei;
  const int* dstA = ei + NE;

  size_t off = 0;
  auto take = [&](size_t bytes)->size_t{ size_t r = off; off += (bytes + 255) & ~(size_t)255; return r; };
  // zero region (memset once per call): degrees, fill counters, BN stats
  size_t o_deg_src = take(NN*4), o_deg_dst = take(NN*4);
  size_t o_fill_src = take(NN*4), o_fill_dst = take(NN*4);
  size_t o_stats0 = take(2*32*4), o_stats1 = take(2*64*4), o_stats2 = take(2*128*4);
  size_t o_statsH1 = take(2*256*4), o_statsH2 = take(2*128*4);
  size_t zero_bytes = off;
  // rest
  size_t o_rp_src = take((NN+1)*4), o_rp_dst = take((NN+1)*4);
  size_t o_eid_src = take((size_t)NE*4), o_eid_dst = take((size_t)NE*4);
  size_t o_starts = take((NGB+1)*4);
  size_t o_t2  = take((size_t)NE*64*4);
  size_t o_Y   = take((size_t)NN*2048*4);
  size_t o_xb  = take((size_t)NN*32*4);
  size_t o_msg = take((size_t)NE*32*4);
  size_t o_h0  = take((size_t)NN*32*4);
  size_t o_hW1 = take((size_t)NN*64*4);
  size_t o_scs1 = take(NN*4), o_scd1 = take(NN*4);
  size_t o_h1  = take((size_t)NN*64*4);
  size_t o_hW2 = take((size_t)NN*128*4);
  size_t o_scs2 = take(NN*4), o_scd2 = take(NN*4);
  size_t o_h2  = take((size_t)NN*128*4);
  size_t o_g   = take(NGB*128*4);
  size_t o_g1  = take(NGB*256*4);
  size_t o_g2  = take(NGB*128*4);

  #define WF(o) ((float*)(ws + (o)))
  #define WI(o) ((int*)(ws + (o)))

  hipMemsetAsync(ws, 0, zero_bytes, stream);
  k_degrees<<<(NE+255)/256,256,0,stream>>>(srcA,dstA,WI(o_deg_src),WI(o_deg_dst));
  k_scan<<<2,1024,0,stream>>>(WI(o_deg_src),WI(o_deg_dst),WI(o_rp_src),WI(o_rp_dst));
  k_fill<<<(NE+255)/256,256,0,stream>>>(srcA,dstA,WI(o_rp_src),WI(o_rp_dst),
                                        WI(o_fill_src),WI(o_fill_dst),WI(o_eid_src),WI(o_eid_dst));
  k_bounds<<<(NN+256)/256,256,0,stream>>>(batch,WI(o_starts));

  k_edge_mlp<<<1024,256,0,stream>>>(ea,We1,be1,We2,be2,WF(o_t2));
  k_y<<<512,256,0,stream>>>(x,We3,be3,WF(o_Y),WF(o_xb));
  k_msg<<<2048,256,0,stream>>>(WF(o_Y),WF(o_xb),WF(o_t2),WI(o_rp_src),WI(o_eid_src),WF(o_msg));
  k_conv<<<640,256,0,stream>>>(WF(o_msg),x,Wroot,bc1,WI(o_rp_dst),WI(o_eid_dst),WF(o_h0));

  k_stats<<<64,256,0,stream>>>(WF(o_h0),NN,32,WF(o_stats0));
  k_gat_linear<32,64><<<640,256,0,stream>>>(WF(o_h0),WF(o_stats0),Wg1,as1,ad1,
                                            WF(o_hW1),WF(o_scs1),WF(o_scd1));
  k_gat_attn<64><<<640,256,0,stream>>>(WF(o_hW1),WF(o_scs1),WF(o_scd1),
                                       WI(o_rp_dst),WI(o_eid_dst),srcA,bg1,WF(o_h1));
  k_stats<<<64,256,0,stream>>>(WF(o_h1),NN,64,WF(o_stats1));
  k_gat_linear<64,128><<<640,256,0,stream>>>(WF(o_h1),WF(o_stats1),Wg2,as2,ad2,
                                             WF(o_hW2),WF(o_scs2),WF(o_scd2));
  k_gat_attn<128><<<640,256,0,stream>>>(WF(o_hW2),WF(o_scs2),WF(o_scd2),
                                        WI(o_rp_dst),WI(o_eid_dst),srcA,bg2,WF(o_h2));
  k_stats<<<64,256,0,stream>>>(WF(o_h2),NN,128,WF(o_stats2));

  k_pool<<<NGB,256,0,stream>>>(WF(o_h2),WF(o_stats2),WI(o_starts),WF(o_g));
  k_head1<<<NGB,256,0,stream>>>(WF(o_g),Wf1,bf1,WF(o_g1));
  k_stats<<<64,256,0,stream>>>(WF(o_g1),NGB,256,WF(o_statsH1));
  k_head2<<<NGB,256,0,stream>>>(WF(o_g1),WF(o_statsH1),Wf2,bf2,WF(o_g2));
  k_stats<<<64,256,0,stream>>>(WF(o_g2),NGB,128,WF(o_statsH2));
  k_head3<<<NGB,256,0,stream>>>(WF(o_g2),WF(o_statsH2),Wf3,bf3,out);
}

// Round 2
// 478.346 us; speedup vs baseline: 1.3015x; 1.3015x over previous
//
#include <hip/hip_runtime.h>

#define NN 10000      // nodes
#define NE 160000     // edges
#define NGB 100       // graphs

typedef __attribute__((ext_vector_type(8))) short s8v;   // 8 x bf16 (4 VGPR)
typedef __attribute__((ext_vector_type(4))) float f4v;   // MFMA accumulator

static __device__ __forceinline__ float lrelu(float v){ return v > 0.f ? v : 0.2f*v; }
static __device__ __forceinline__ unsigned short f2bf(float f){
  unsigned u = __float_as_uint(f);
  u += 0x7fffu + ((u >> 16) & 1u);
  return (unsigned short)(u >> 16);
}
static __device__ __forceinline__ float bf2f(unsigned short h){
  return __uint_as_float(((unsigned)h) << 16);
}
static __device__ __forceinline__ unsigned pack2(float a, float b){
  return (unsigned)f2bf(a) | ((unsigned)f2bf(b) << 16);
}

// ---------------- CSR build ----------------
__global__ __launch_bounds__(256) void k_degrees(const int* __restrict__ src, const int* __restrict__ dst,
                                                 int* deg_src, int* deg_dst){
  int i = blockIdx.x*256 + threadIdx.x;
  if (i < NE){ atomicAdd(&deg_src[src[i]],1); atomicAdd(&deg_dst[dst[i]],1); }
}

__global__ __launch_bounds__(1024) void k_scan(const int* __restrict__ deg_src, const int* __restrict__ deg_dst,
                                               int* rp_src, int* rp_dst){
  const int* deg = (blockIdx.x==0) ? deg_src : deg_dst;
  int* rp = (blockIdx.x==0) ? rp_src : rp_dst;
  __shared__ int part[1024];
  int tid = threadIdx.x;
  const int per = (NN + 1023)/1024;   // 10
  int base = tid*per;
  int s = 0;
  for (int i=0;i<per;i++){ int idx=base+i; if (idx<NN) s += deg[idx]; }
  part[tid]=s; __syncthreads();
  for (int off=1; off<1024; off<<=1){
    int v = part[tid];
    int add = (tid>=off) ? part[tid-off] : 0;
    __syncthreads();
    part[tid] = v + add;
    __syncthreads();
  }
  int run = (tid==0) ? 0 : part[tid-1];
  for (int i=0;i<per;i++){ int idx=base+i; if (idx<NN){ rp[idx]=run; run += deg[idx]; } }
  if (tid==1023) rp[NN] = part[1023];
}

__global__ __launch_bounds__(256) void k_fill(const int* __restrict__ src, const int* __restrict__ dst,
                       const int* __restrict__ rp_src, const int* __restrict__ rp_dst,
                       int* fill_src, int* fill_dst, int* eid_src, int* eid_dst){
  int i = blockIdx.x*256 + threadIdx.x;
  if (i < NE){
    int s=src[i]; int p=rp_src[s]+atomicAdd(&fill_src[s],1); eid_src[p]=i;
    int d=dst[i]; int q=rp_dst[d]+atomicAdd(&fill_dst[d],1); eid_dst[q]=i;
  }
}

__global__ __launch_bounds__(256) void k_bounds(const int* __restrict__ batch, int* starts){
  int n = blockIdx.x*256 + threadIdx.x;
  if (n > NN) return;
  int cur  = (n==NN) ? NGB : batch[n];
  int prev = (n==0)  ? -1  : batch[n-1];
  for (int b=prev+1; b<=cur; b++) if (b<=NGB) starts[b]=n;
}

// ---------------- weight pack for MFMA edge MLP ----------------
// W1p: layer1 A-operand = We1^T tiles, bias folded at k==16 (edge feature "1").
//   frag (j=0..7 out-tiles): lane l, elem jj: k=(l>>4)*8+jj, out=j*16+(l&15)
// W2p: layer2 A-operand = We2^T tiles (t=0..3 K-steps, jo=0..3 out-tiles)
__global__ __launch_bounds__(256) void k_pack(const float* __restrict__ We1, const float* __restrict__ be1,
    const float* __restrict__ We2, unsigned short* __restrict__ W1p, unsigned short* __restrict__ W2p){
  int tid = threadIdx.x;
  for (int idx=tid; idx<512; idx+=256){
    int j=idx>>6, l=idx&63, col=l&15, g=l>>4;
    int out = j*16+col;
    #pragma unroll
    for (int jj=0;jj<8;jj++){
      int k = g*8+jj;
      float v = (k<16) ? We1[k*128+out] : (k==16 ? be1[out] : 0.f);
      W1p[idx*8+jj] = f2bf(v);
    }
  }
  for (int idx=tid; idx<1024; idx+=256){
    int ft=idx>>6, l=idx&63, col=l&15, g=l>>4;
    int t=ft>>2, jo=ft&3;
    int out = jo*16+col;
    #pragma unroll
    for (int jj=0;jj<8;jj++){
      int k = t*32+g*8+jj;
      W2p[idx*8+jj] = f2bf(We2[k*64+out]);
    }
  }
}

// ---------------- EdgeMLP via MFMA: t2[E,64] = relu( relu(ea@We1+be1) @ We2 + be2 ) ----------------
// 4 waves/block, 16 edges/wave/iter. Both GEMMs computed transposed (D=[outs x edges])
// so layer1 C-frag (col=lane&15=edge) matches layer2 B-operand via a 4KB/wave LDS buffer.
__global__ __launch_bounds__(256) void k_edge_mlp2(const float* __restrict__ ea,
    const unsigned short* __restrict__ W1p, const unsigned short* __restrict__ W2p,
    const float* __restrict__ be2, float* __restrict__ t2){
  __shared__ unsigned short st1[4*2048];   // [wave][16 edges][128 k] bf16, XOR-swizzled
  int tid=threadIdx.x, wave=tid>>6, lane=tid&63;
  int c = lane&15, g = lane>>4;
  s8v w1f[8], w2f[16];
  #pragma unroll
  for (int j=0;j<8;j++)  w1f[j] = *(const s8v*)(W1p + (size_t)(j*64+lane)*8);
  #pragma unroll
  for (int q=0;q<16;q++) w2f[q] = *(const s8v*)(W2p + (size_t)(q*64+lane)*8);
  float be2v[16];
  #pragma unroll
  for (int jo=0;jo<4;jo++)
    #pragma unroll
    for (int r=0;r<4;r++) be2v[jo*4+r] = be2[jo*16+g*4+r];
  char* myld = (char*)(st1 + wave*2048);
  const f4v fzero = {0.f,0.f,0.f,0.f};

  for (int base = blockIdx.x*64; base < NE; base += gridDim.x*64){
    int e0 = base + wave*16;
    // B-operand for layer1: ea^T, col=edge(c), k=g*8+jj ; k==16 -> 1.0 (bias slot)
    s8v eaf = {0,0,0,0,0,0,0,0};
    if (g < 2){
      const float* p = ea + (size_t)(e0+c)*16 + g*8;
      float4 a = *(const float4*)p;
      float4 b = *(const float4*)(p+4);
      eaf[0]=(short)f2bf(a.x); eaf[1]=(short)f2bf(a.y); eaf[2]=(short)f2bf(a.z); eaf[3]=(short)f2bf(a.w);
      eaf[4]=(short)f2bf(b.x); eaf[5]=(short)f2bf(b.y); eaf[6]=(short)f2bf(b.z); eaf[7]=(short)f2bf(b.w);
    } else if (g == 2){
      eaf[0] = (short)0x3f80;  // bf16(1.0)
    }
    // layer1: D[out=j*16+g*4+r][edge=c]
    f4v acc1[8];
    #pragma unroll
    for (int j=0;j<8;j++)
      acc1[j] = __builtin_amdgcn_mfma_f32_16x16x32_bf16(w1f[j], eaf, fzero, 0, 0, 0);
    // relu -> bf16 -> LDS t1[edge=c][k=j*16+g*4+r], byte = c*256 + (j*32+g*8) ^ (c<<4)
    #pragma unroll
    for (int j=0;j<8;j++){
      unsigned lo = pack2(fmaxf(acc1[j][0],0.f), fmaxf(acc1[j][1],0.f));
      unsigned hi = pack2(fmaxf(acc1[j][2],0.f), fmaxf(acc1[j][3],0.f));
      unsigned off = (unsigned)(c*256 + ((j*32 + g*8) ^ (c<<4)));
      *(uint2*)(myld + off) = make_uint2(lo, hi);
    }
    __syncthreads();
    // layer2: B-operand t1^T from LDS: col=edge(c), k=t*32+g*8+jj
    f4v acc2[4];
    #pragma unroll
    for (int jo=0;jo<4;jo++) acc2[jo] = fzero;
    #pragma unroll
    for (int t=0;t<4;t++){
      unsigned off = (unsigned)(c*256 + ((t*64 + g*16) ^ (c<<4)));
      s8v b2 = *(const s8v*)(myld + off);
      #pragma unroll
      for (int jo=0;jo<4;jo++)
        acc2[jo] = __builtin_amdgcn_mfma_f32_16x16x32_bf16(w2f[t*4+jo], b2, acc2[jo], 0, 0, 0);
    }
    // store: t2[edge=c][out=jo*16+g*4+r] as float4
    float* orow = t2 + (size_t)(e0+c)*64;
    #pragma unroll
    for (int jo=0;jo<4;jo++){
      f4v v;
      #pragma unroll
      for (int r=0;r<4;r++) v[r] = fmaxf(acc2[jo][r] + be2v[jo*4+r], 0.f);
      *(f4v*)(orow + jo*16 + g*4) = v;
    }
    __syncthreads();
  }
}

// ---------------- Y[n, k*32+o] (bf16) ; xb[n,o] = x@be3-fold ----------------
__global__ __launch_bounds__(256) void k_y(const float* __restrict__ x,
    const float* __restrict__ We3, const float* __restrict__ be3,
    unsigned short* __restrict__ Y, float* __restrict__ xb){
  int jb = blockIdx.x & 7;
  int cb = blockIdx.x >> 3;
  int nchunks = gridDim.x >> 3;
  int j = jb*256 + threadIdx.x;   // 0..2047
  int k = j >> 5, o = j & 31;
  float w[32];
  #pragma unroll
  for (int f=0;f<32;f++) w[f] = We3[k*1024 + f*32 + o];
  int per = (NN + nchunks - 1)/nchunks;
  int n0 = cb*per;
  int n1 = min(n0+per, NN);
  for (int n=n0;n<n1;n++){
    const float* xr = x + (size_t)n*32;
    float acc = 0.f;
    #pragma unroll
    for (int f=0;f<32;f++) acc += xr[f]*w[f];
    Y[(size_t)n*2048 + j] = f2bf(acc);
  }
  if (jb == 0){
    int oo = threadIdx.x & 31;
    int sub = threadIdx.x >> 5;
    float wb[32];
    #pragma unroll
    for (int f=0;f<32;f++) wb[f] = be3[f*32+oo];
    for (int n=n0+sub;n<n1;n+=8){
      const float* xr = x + (size_t)n*32;
      float acc = 0.f;
      #pragma unroll
      for (int f=0;f<32;f++) acc += xr[f]*wb[f];
      xb[(size_t)n*32+oo] = acc;
    }
  }
}

// ---------------- msg[e,o] = xb[src,o] + sum_k t2[e,k]*Y[src, k*32+o] ----------------
__global__ __launch_bounds__(256) void k_msg(const unsigned short* __restrict__ Y,
    const float* __restrict__ xb, const float* __restrict__ t2,
    const int* __restrict__ rp_src, const int* __restrict__ eid_src,
    float* __restrict__ msg){
  __shared__ float Ys[2048];
  __shared__ float t2s[8][64];
  __shared__ float xbs[32];
  for (int n = blockIdx.x; n < NN; n += gridDim.x){
    int beg = rp_src[n], end = rp_src[n+1];
    int deg = end - beg;
    if (deg == 0) continue;                       // uniform per block
    const unsigned* Yrow = (const unsigned*)(Y + (size_t)n*2048);
    for (int i=threadIdx.x;i<1024;i+=256){
      unsigned u = Yrow[i];
      Ys[2*i]   = bf2f((unsigned short)(u & 0xffffu));
      Ys[2*i+1] = bf2f((unsigned short)(u >> 16));
    }
    if (threadIdx.x < 32) xbs[threadIdx.x] = xb[(size_t)n*32+threadIdx.x];
    __syncthreads();
    int o = threadIdx.x & 31;
    int slot = threadIdx.x >> 5;                  // 0..7
    for (int base=0; base<deg; base+=8){
      int nb = min(8, deg-base);
      for (int i=threadIdx.x; i<nb*64; i+=256){
        int sl = i>>6, kk = i&63;
        int e = eid_src[beg+base+sl];
        t2s[sl][kk] = t2[(size_t)e*64+kk];
      }
      __syncthreads();
      if (slot < nb){
        int e = eid_src[beg+base+slot];
        float acc = xbs[o];
        #pragma unroll
        for (int k4=0;k4<16;k4++){
          float4 tv = *reinterpret_cast<const float4*>(&t2s[slot][k4*4]);
          acc += tv.x*Ys[(k4*4+0)*32+o];
          acc += tv.y*Ys[(k4*4+1)*32+o];
          acc += tv.z*Ys[(k4*4+2)*32+o];
          acc += tv.w*Ys[(k4*4+3)*32+o];
        }
        msg[(size_t)e*32+o] = acc;
      }
      __syncthreads();
    }
  }
}

// ---------------- h0raw = segsum(msg by dst) + x@Wroot + bc1 ----------------
__global__ __launch_bounds__(256) void k_conv(const float* __restrict__ msg,
    const float* __restrict__ x, const float* __restrict__ Wroot, const float* __restrict__ bc1,
    const int* __restrict__ rp_dst, const int* __restrict__ eid_dst,
    float* __restrict__ h0raw){
  __shared__ float sW[32*32];
  __shared__ float sb[32];
  int tid = threadIdx.x;
  for (int i=tid;i<1024;i+=256) sW[i]=Wroot[i];
  if (tid<32) sb[tid]=bc1[tid];
  __syncthreads();
  int wave=tid>>6, lane=tid&63;
  int f=lane&31, half=lane>>5;
  for (int n = blockIdx.x*4+wave; n < NN; n += gridDim.x*4){
    int beg=rp_dst[n], end=rp_dst[n+1];
    float acc=0.f;
    for (int i=beg+half;i<end;i+=2){
      int e = eid_dst[i];
      acc += msg[(size_t)e*32+f];
    }
    acc += __shfl_xor(acc,32);
    if (half==0){
      const float* xr = x + (size_t)n*32;
      float r = sb[f];
      #pragma unroll
      for (int k=0;k<32;k++) r += xr[k]*sW[k*32+f];
      h0raw[(size_t)n*32+f] = acc + r;
    }
  }
}

// ---------------- column stats (sum, sumsq) for BN; stats must be pre-zeroed ----------------
__global__ __launch_bounds__(256) void k_stats(const float* __restrict__ buf, int nrows, int ncols,
                                               float* __restrict__ stats){
  int tid = threadIdx.x;
  int c  = tid % ncols;
  int r0 = tid / ncols;
  int rp = 256 / ncols;
  float s1=0.f, s2=0.f;
  for (long long base=(long long)blockIdx.x*rp; base<nrows; base+=(long long)gridDim.x*rp){
    int r = (int)base + r0;
    if (r < nrows){
      float v = buf[(size_t)r*ncols + c];
      s1 += v; s2 += v*v;
    }
  }
  __shared__ float A[256], B[256];
  A[tid]=s1; B[tid]=s2; __syncthreads();
  if (tid < ncols){
    float t1=0.f, t2=0.f;
    for (int gg=0; gg<256/ncols; gg++){ t1 += A[gg*ncols+tid]; t2 += B[gg*ncols+tid]; }
    atomicAdd(&stats[tid], t1);
    atomicAdd(&stats[ncols+tid], t2);
  }
}

// ---------------- GAT linear: in = relu(bn(raw)); hW = in@W; sc_s = hW@a_s; sc_d = hW@a_d ----------------
template<int FIN, int FOUT>
__global__ __launch_bounds__(256) void k_gat_linear(const float* __restrict__ raw,
    const float* __restrict__ stats, const float* __restrict__ W,
    const float* __restrict__ avs, const float* __restrict__ avd,
    float* __restrict__ hW, float* __restrict__ sc_s, float* __restrict__ sc_d){
  __shared__ float sW[FIN*FOUT];
  __shared__ float sA[FOUT], sD[FOUT];
  __shared__ float sScale[FIN], sShift[FIN];
  __shared__ float sIn[4][FIN];
  int tid = threadIdx.x;
  for (int i=tid;i<FIN*FOUT;i+=256) sW[i]=W[i];
  if (tid<FOUT){ sA[tid]=avs[tid]; sD[tid]=avd[tid]; }
  if (tid<FIN){
    float m = stats[tid]*(1.f/NN);
    float v = stats[FIN+tid]*(1.f/NN) - m*m;
    float s = rsqrtf(v + 1e-5f);
    sScale[tid]=s; sShift[tid]=-m*s;
  }
  __syncthreads();
  int wave=tid>>6, lane=tid&63;
  for (int nb = blockIdx.x*4; nb < NN; nb += gridDim.x*4){
    int n = nb + wave;
    bool act = n < NN;
    if (act){
      for (int ff=lane; ff<FIN; ff+=64){
        float vv = raw[(size_t)n*FIN+ff]*sScale[ff]+sShift[ff];
        sIn[wave][ff] = fmaxf(vv, 0.f);
      }
    }
    __syncthreads();
    if (act){
      float out0=0.f, out1=0.f;
      #pragma unroll
      for (int ff=0; ff<FIN; ff++){
        float xv = sIn[wave][ff];
        out0 += xv*sW[ff*FOUT+lane];
        if constexpr (FOUT > 64) out1 += xv*sW[ff*FOUT+lane+64];
      }
      hW[(size_t)n*FOUT+lane] = out0;
      float ps = out0*sA[lane], pd = out0*sD[lane];
      if constexpr (FOUT > 64){
        hW[(size_t)n*FOUT+lane+64] = out1;
        ps += out1*sA[lane+64]; pd += out1*sD[lane+64];
      }
      #pragma unroll
      for (int off=32;off>0;off>>=1){ ps += __shfl_down(ps,off); pd += __shfl_down(pd,off); }
      if (lane==0){ sc_s[n]=ps; sc_d[n]=pd; }
    }
    __syncthreads();
  }
}

// ---------------- GAT attention + aggregate ----------------
template<int F>
__global__ __launch_bounds__(256) void k_gat_attn(const float* __restrict__ hW,
    const float* __restrict__ sc_s, const float* __restrict__ sc_d,
    const int* __restrict__ rp_dst, const int* __restrict__ eid_dst,
    const int* __restrict__ src, const float* __restrict__ bias,
    float* __restrict__ outraw){
  int tid=threadIdx.x;
  int wave=tid>>6, lane=tid&63;
  for (int n = blockIdx.x*4+wave; n < NN; n += gridDim.x*4){
    int beg=rp_dst[n], end=rp_dst[n+1];
    float scd = sc_d[n];
    float sself = lrelu(sc_s[n]+scd);
    float m = sself;
    for (int i=beg+lane;i<end;i+=64){
      int e=eid_dst[i];
      m = fmaxf(m, lrelu(sc_s[src[e]]+scd));
    }
    #pragma unroll
    for (int off=32;off>0;off>>=1) m = fmaxf(m, __shfl_xor(m,off));
    float ssum = 0.f;
    for (int i=beg+lane;i<end;i+=64){
      int e=eid_dst[i];
      ssum += expf(lrelu(sc_s[src[e]]+scd)-m);
    }
    #pragma unroll
    for (int off=32;off>0;off>>=1) ssum += __shfl_xor(ssum,off);
    float pself = expf(sself-m);
    float inv = 1.f/(ssum + pself + 1e-16f);
    float acc0=0.f, acc1=0.f;
    for (int i=beg;i<end;i++){
      int e=eid_dst[i];
      int s=src[e];
      float p = expf(lrelu(sc_s[s]+scd)-m);
      acc0 += p*hW[(size_t)s*F+lane];
      if constexpr (F > 64) acc1 += p*hW[(size_t)s*F+lane+64];
    }
    acc0 += pself*hW[(size_t)n*F+lane];
    outraw[(size_t)n*F+lane] = acc0*inv + bias[lane];
    if constexpr (F > 64){
      acc1 += pself*hW[(size_t)n*F+lane+64];
      outraw[(size_t)n*F+lane+64] = acc1*inv + bias[lane+64];
    }
  }
}

// ---------------- mean pool with bn+relu on read ----------------
__global__ __launch_bounds__(256) void k_pool(const float* __restrict__ h2raw,
    const float* __restrict__ stats, const int* __restrict__ starts,
    float* __restrict__ g){
  __shared__ float sc[128], sh[128];
  __shared__ float red[256];
  int b=blockIdx.x, t=threadIdx.x;
  if (t<128){
    float m = stats[t]*(1.f/NN);
    float v = stats[128+t]*(1.f/NN) - m*m;
    float s = rsqrtf(v+1e-5f);
    sc[t]=s; sh[t]=-m*s;
  }
  __syncthreads();
  int s0=starts[b], s1=starts[b+1];
  int f=t&127, half=t>>7;
  float acc=0.f;
  for (int n=s0+half;n<s1;n+=2){
    float v = h2raw[(size_t)n*128+f]*sc[f]+sh[f];
    acc += fmaxf(v,0.f);
  }
  red[t]=acc; __syncthreads();
  if (half==0){
    int cnt = s1-s0;
    g[b*128+f] = (red[f]+red[128+f]) / fmaxf((float)cnt, 1.f);
  }
}

// ---------------- FC head ----------------
__global__ __launch_bounds__(256) void k_head1(const float* __restrict__ g,
    const float* __restrict__ Wf1, const float* __restrict__ bf1, float* __restrict__ g1){
  __shared__ float sg[128];
  int r=blockIdx.x, t=threadIdx.x;
  if (t<128) sg[t]=g[r*128+t];
  __syncthreads();
  float acc=bf1[t];
  #pragma unroll 4
  for (int k=0;k<128;k++) acc += sg[k]*Wf1[k*256+t];
  g1[r*256+t]=acc;
}

__global__ __launch_bounds__(256) void k_head2(const float* __restrict__ g1,
    const float* __restrict__ stats, const float* __restrict__ Wf2,
    const float* __restrict__ bf2, float* __restrict__ g2){
  __shared__ float sin_[256];
  int r=blockIdx.x, t=threadIdx.x;
  float m = stats[t]*(1.f/NGB);
  float v = stats[256+t]*(1.f/NGB) - m*m;
  float val = (g1[r*256+t]-m)*rsqrtf(v+1e-5f);
  sin_[t]=fmaxf(val,0.f);
  __syncthreads();
  if (t<128){
    float acc=bf2[t];
    #pragma unroll 4
    for (int k=0;k<256;k++) acc += sin_[k]*Wf2[k*128+t];
    g2[r*128+t]=acc;
  }
}

__global__ __launch_bounds__(256) void k_head3(const float* __restrict__ g2,
    const float* __restrict__ stats, const float* __restrict__ Wf3,
    const float* __restrict__ bf3, float* __restrict__ out){
  __shared__ float sin_[128];
  int r=blockIdx.x, t=threadIdx.x;
  if (t<128){
    float m = stats[t]*(1.f/NGB);
    float v = stats[128+t]*(1.f/NGB) - m*m;
    float val = (g2[r*128+t]-m)*rsqrtf(v+1e-5f);
    sin_[t]=fmaxf(val,0.f);
  }
  __syncthreads();
  if (t<64){
    float acc=bf3[t];
    #pragma unroll 4
    for (int k=0;k<128;k++) acc += sin_[k]*Wf3[k*64+t];
    out[r*64+t]=acc;
  }
}

extern "C" void kernel_launch(void* const* d_in, const int* in_sizes, int n_in,
                              void* d_out, int out_size, void* d_ws, size_t ws_size,
                              hipStream_t stream){
  const float* x    = (const float*)d_in[0];
  const int*   ei   = (const int*)d_in[1];
  const float* ea   = (const float*)d_in[2];
  const int*   batch= (const int*)d_in[3];
  const float* We1=(const float*)d_in[4];  const float* be1=(const float*)d_in[5];
  const float* We2=(const float*)d_in[6];  const float* be2=(const float*)d_in[7];
  const float* We3=(const float*)d_in[8];  const float* be3=(const float*)d_in[9];
  const float* Wroot=(const float*)d_in[10]; const float* bc1=(const float*)d_in[11];
  const float* Wg1=(const float*)d_in[12]; const float* as1=(const float*)d_in[13];
  const float* ad1=(const float*)d_in[14]; const float* bg1=(const float*)d_in[15];
  const float* Wg2=(const float*)d_in[16]; const float* as2=(const float*)d_in[17];
  const float* ad2=(const float*)d_in[18]; const float* bg2=(const float*)d_in[19];
  const float* Wf1=(const float*)d_in[20]; const float* bf1=(const float*)d_in[21];
  const float* Wf2=(const float*)d_in[22]; const float* bf2=(const float*)d_in[23];
  const float* Wf3=(const float*)d_in[24]; const float* bf3=(const float*)d_in[25];
  (void)in_sizes; (void)n_in; (void)out_size; (void)ws_size;
  float* out = (float*)d_out;
  char* ws = (char*)d_ws;
  const int* srcA = ei;
  const int* dstA = ei + NE;

  size_t off = 0;
  auto take = [&](size_t bytes)->size_t{ size_t r = off; off += (bytes + 255) & ~(size_t)255; return r; };
  // zero region (memset once per call): degrees, fill counters, BN stats
  size_t o_deg_src = take(NN*4), o_deg_dst = take(NN*4);
  size_t o_fill_src = take(NN*4), o_fill_dst = take(NN*4);
  size_t o_stats0 = take(2*32*4), o_stats1 = take(2*64*4), o_stats2 = take(2*128*4);
  size_t o_statsH1 = take(2*256*4), o_statsH2 = take(2*128*4);
  size_t zero_bytes = off;
  // rest
  size_t o_rp_src = take((NN+1)*4), o_rp_dst = take((NN+1)*4);
  size_t o_eid_src = take((size_t)NE*4), o_eid_dst = take((size_t)NE*4);
  size_t o_starts = take((NGB+1)*4);
  size_t o_W1p = take(4096*2);
  size_t o_W2p = take(8192*2);
  size_t o_t2  = take((size_t)NE*64*4);
  size_t o_Y   = take((size_t)NN*2048*2);          // bf16
  size_t o_xb  = take((size_t)NN*32*4);
  size_t o_msg = take((size_t)NE*32*4);
  size_t o_h0  = take((size_t)NN*32*4);
  size_t o_hW1 = take((size_t)NN*64*4);
  size_t o_scs1 = take(NN*4), o_scd1 = take(NN*4);
  size_t o_h1  = take((size_t)NN*64*4);
  size_t o_hW2 = take((size_t)NN*128*4);
  size_t o_scs2 = take(NN*4), o_scd2 = take(NN*4);
  size_t o_h2  = take((size_t)NN*128*4);
  size_t o_g   = take(NGB*128*4);
  size_t o_g1  = take(NGB*256*4);
  size_t o_g2  = take(NGB*128*4);

  #define WF(o) ((float*)(ws + (o)))
  #define WI(o) ((int*)(ws + (o)))
  #define WU(o) ((unsigned short*)(ws + (o)))

  hipMemsetAsync(ws, 0, zero_bytes, stream);
  k_degrees<<<(NE+255)/256,256,0,stream>>>(srcA,dstA,WI(o_deg_src),WI(o_deg_dst));
  k_scan<<<2,1024,0,stream>>>(WI(o_deg_src),WI(o_deg_dst),WI(o_rp_src),WI(o_rp_dst));
  k_fill<<<(NE+255)/256,256,0,stream>>>(srcA,dstA,WI(o_rp_src),WI(o_rp_dst),
                                        WI(o_fill_src),WI(o_fill_dst),WI(o_eid_src),WI(o_eid_dst));
  k_bounds<<<(NN+256)/256,256,0,stream>>>(batch,WI(o_starts));

  k_pack<<<1,256,0,stream>>>(We1,be1,We2,WU(o_W1p),WU(o_W2p));
  k_edge_mlp2<<<500,256,0,stream>>>(ea,WU(o_W1p),WU(o_W2p),be2,WF(o_t2));
  k_y<<<512,256,0,stream>>>(x,We3,be3,WU(o_Y),WF(o_xb));
  k_msg<<<2048,256,0,stream>>>(WU(o_Y),WF(o_xb),WF(o_t2),WI(o_rp_src),WI(o_eid_src),WF(o_msg));
  k_conv<<<640,256,0,stream>>>(WF(o_msg),x,Wroot,bc1,WI(o_rp_dst),WI(o_eid_dst),WF(o_h0));

  k_stats<<<64,256,0,stream>>>(WF(o_h0),NN,32,WF(o_stats0));
  k_gat_linear<32,64><<<640,256,0,stream>>>(WF(o_h0),WF(o_stats0),Wg1,as1,ad1,
                                            WF(o_hW1),WF(o_scs1),WF(o_scd1));
  k_gat_attn<64><<<640,256,0,stream>>>(WF(o_hW1),WF(o_scs1),WF(o_scd1),
                                       WI(o_rp_dst),WI(o_eid_dst),srcA,bg1,WF(o_h1));
  k_stats<<<64,256,0,stream>>>(WF(o_h1),NN,64,WF(o_stats1));
  k_gat_linear<64,128><<<640,256,0,stream>>>(WF(o_h1),WF(o_stats1),Wg2,as2,ad2,
                                             WF(o_hW2),WF(o_scs2),WF(o_scd2));
  k_gat_attn<128><<<640,256,0,stream>>>(WF(o_hW2),WF(o_scs2),WF(o_scd2),
                                        WI(o_rp_dst),WI(o_eid_dst),srcA,bg2,WF(o_h2));
  k_stats<<<64,256,0,stream>>>(WF(o_h2),NN,128,WF(o_stats2));

  k_pool<<<NGB,256,0,stream>>>(WF(o_h2),WF(o_stats2),WI(o_starts),WF(o_g));
  k_head1<<<NGB,256,0,stream>>>(WF(o_g),Wf1,bf1,WF(o_g1));
  k_stats<<<64,256,0,stream>>>(WF(o_g1),NGB,256,WF(o_statsH1));
  k_head2<<<NGB,256,0,stream>>>(WF(o_g1),WF(o_statsH1),Wf2,bf2,WF(o_g2));
  k_stats<<<64,256,0,stream>>>(WF(o_g2),NGB,128,WF(o_statsH2));
  k_head3<<<NGB,256,0,stream>>>(WF(o_g2),WF(o_statsH2),Wf3,bf3,out);
}

// Round 3
// 395.903 us; speedup vs baseline: 1.5725x; 1.2082x over previous
//
#include <hip/hip_runtime.h>

#define NN 10000      // nodes
#define NE 160000     // edges
#define NGB 100       // graphs

typedef __attribute__((ext_vector_type(8))) short s8v;   // 8 x bf16 (4 VGPR)
typedef __attribute__((ext_vector_type(4))) float f4v;   // MFMA accumulator

static __device__ __forceinline__ float lrelu(float v){ return v > 0.f ? v : 0.2f*v; }
static __device__ __forceinline__ unsigned short f2bf(float f){
  unsigned u = __float_as_uint(f);
  u += 0x7fffu + ((u >> 16) & 1u);
  return (unsigned short)(u >> 16);
}
static __device__ __forceinline__ unsigned pack2(float a, float b){
  return (unsigned)f2bf(a) | ((unsigned)f2bf(b) << 16);
}

// ---------------- CSR build ----------------
__global__ __launch_bounds__(256) void k_degrees(const int* __restrict__ src, const int* __restrict__ dst,
                                                 int* deg_src, int* deg_dst){
  int i = blockIdx.x*256 + threadIdx.x;
  if (i < NE){ atomicAdd(&deg_src[src[i]],1); atomicAdd(&deg_dst[dst[i]],1); }
}

__global__ __launch_bounds__(1024) void k_scan(const int* __restrict__ deg_src, const int* __restrict__ deg_dst,
                                               int* rp_src, int* rp_dst){
  const int* deg = (blockIdx.x==0) ? deg_src : deg_dst;
  int* rp = (blockIdx.x==0) ? rp_src : rp_dst;
  __shared__ int part[1024];
  int tid = threadIdx.x;
  const int per = (NN + 1023)/1024;   // 10
  int base = tid*per;
  int s = 0;
  for (int i=0;i<per;i++){ int idx=base+i; if (idx<NN) s += deg[idx]; }
  part[tid]=s; __syncthreads();
  for (int off=1; off<1024; off<<=1){
    int v = part[tid];
    int add = (tid>=off) ? part[tid-off] : 0;
    __syncthreads();
    part[tid] = v + add;
    __syncthreads();
  }
  int run = (tid==0) ? 0 : part[tid-1];
  for (int i=0;i<per;i++){ int idx=base+i; if (idx<NN){ rp[idx]=run; run += deg[idx]; } }
  if (tid==1023) rp[NN] = part[1023];
}

// pos_src[e]: slot of edge e in CSR-src order; dstp[p]=dst of edge at src-slot p;
// srcd[q]=src of edge at dst-slot q.
__global__ __launch_bounds__(256) void k_fill(const int* __restrict__ src, const int* __restrict__ dst,
                       const int* __restrict__ rp_src, const int* __restrict__ rp_dst,
                       int* fill_src, int* fill_dst, int* pos_src, int* dstp, int* srcd){
  int i = blockIdx.x*256 + threadIdx.x;
  if (i < NE){
    int s=src[i], d=dst[i];
    int p=rp_src[s]+atomicAdd(&fill_src[s],1); pos_src[i]=p; dstp[p]=d;
    int q=rp_dst[d]+atomicAdd(&fill_dst[d],1); srcd[q]=s;
  }
}

__global__ __launch_bounds__(256) void k_bounds(const int* __restrict__ batch, int* starts){
  int n = blockIdx.x*256 + threadIdx.x;
  if (n > NN) return;
  int cur  = (n==NN) ? NGB : batch[n];
  int prev = (n==0)  ? -1  : batch[n-1];
  for (int b=prev+1; b<=cur; b++) if (b<=NGB) starts[b]=n;
}

// ---------------- weight pack for MFMA edge MLP ----------------
__global__ __launch_bounds__(256) void k_pack(const float* __restrict__ We1, const float* __restrict__ be1,
    const float* __restrict__ We2, unsigned short* __restrict__ W1p, unsigned short* __restrict__ W2p){
  int tid = threadIdx.x;
  for (int idx=tid; idx<512; idx+=256){
    int j=idx>>6, l=idx&63, col=l&15, g=l>>4;
    int out = j*16+col;
    #pragma unroll
    for (int jj=0;jj<8;jj++){
      int k = g*8+jj;
      float v = (k<16) ? We1[k*128+out] : (k==16 ? be1[out] : 0.f);
      W1p[idx*8+jj] = f2bf(v);
    }
  }
  for (int idx=tid; idx<1024; idx+=256){
    int ft=idx>>6, l=idx&63, col=l&15, g=l>>4;
    int t=ft>>2, jo=ft&3;
    int out = jo*16+col;
    #pragma unroll
    for (int jj=0;jj<8;jj++){
      int k = t*32+g*8+jj;
      W2p[idx*8+jj] = f2bf(We2[k*64+out]);
    }
  }
}

// ---------------- EdgeMLP via MFMA -> t2 rows scattered into CSR-src order ----------------
__global__ __launch_bounds__(256) void k_edge_mlp2(const float* __restrict__ ea,
    const unsigned short* __restrict__ W1p, const unsigned short* __restrict__ W2p,
    const float* __restrict__ be2, const int* __restrict__ pos_src, float* __restrict__ t2p){
  __shared__ unsigned short st1[4*2048];   // [wave][16 edges][128 k] bf16, XOR-swizzled
  int tid=threadIdx.x, wave=tid>>6, lane=tid&63;
  int c = lane&15, g = lane>>4;
  s8v w1f[8], w2f[16];
  #pragma unroll
  for (int j=0;j<8;j++)  w1f[j] = *(const s8v*)(W1p + (size_t)(j*64+lane)*8);
  #pragma unroll
  for (int q=0;q<16;q++) w2f[q] = *(const s8v*)(W2p + (size_t)(q*64+lane)*8);
  float be2v[16];
  #pragma unroll
  for (int jo=0;jo<4;jo++)
    #pragma unroll
    for (int r=0;r<4;r++) be2v[jo*4+r] = be2[jo*16+g*4+r];
  char* myld = (char*)(st1 + wave*2048);
  const f4v fzero = {0.f,0.f,0.f,0.f};

  for (int base = blockIdx.x*64; base < NE; base += gridDim.x*64){
    int e0 = base + wave*16;
    s8v eaf = {0,0,0,0,0,0,0,0};
    if (g < 2){
      const float* p = ea + (size_t)(e0+c)*16 + g*8;
      float4 a = *(const float4*)p;
      float4 b = *(const float4*)(p+4);
      eaf[0]=(short)f2bf(a.x); eaf[1]=(short)f2bf(a.y); eaf[2]=(short)f2bf(a.z); eaf[3]=(short)f2bf(a.w);
      eaf[4]=(short)f2bf(b.x); eaf[5]=(short)f2bf(b.y); eaf[6]=(short)f2bf(b.z); eaf[7]=(short)f2bf(b.w);
    } else if (g == 2){
      eaf[0] = (short)0x3f80;  // bf16(1.0) bias slot
    }
    f4v acc1[8];
    #pragma unroll
    for (int j=0;j<8;j++)
      acc1[j] = __builtin_amdgcn_mfma_f32_16x16x32_bf16(w1f[j], eaf, fzero, 0, 0, 0);
    #pragma unroll
    for (int j=0;j<8;j++){
      unsigned lo = pack2(fmaxf(acc1[j][0],0.f), fmaxf(acc1[j][1],0.f));
      unsigned hi = pack2(fmaxf(acc1[j][2],0.f), fmaxf(acc1[j][3],0.f));
      unsigned off = (unsigned)(c*256 + ((j*32 + g*8) ^ (c<<4)));
      *(uint2*)(myld + off) = make_uint2(lo, hi);
    }
    __syncthreads();
    f4v acc2[4];
    #pragma unroll
    for (int jo=0;jo<4;jo++) acc2[jo] = fzero;
    #pragma unroll
    for (int t=0;t<4;t++){
      unsigned off = (unsigned)(c*256 + ((t*64 + g*16) ^ (c<<4)));
      s8v b2 = *(const s8v*)(myld + off);
      #pragma unroll
      for (int jo=0;jo<4;jo++)
        acc2[jo] = __builtin_amdgcn_mfma_f32_16x16x32_bf16(w2f[t*4+jo], b2, acc2[jo], 0, 0, 0);
    }
    int pos = pos_src[e0+c];
    float* orow = t2p + (size_t)pos*64;
    #pragma unroll
    for (int jo=0;jo<4;jo++){
      f4v v;
      #pragma unroll
      for (int r=0;r<4;r++) v[r] = fmaxf(acc2[jo][r] + be2v[jo*4+r], 0.f);
      *(f4v*)(orow + jo*16 + g*4) = v;
    }
    __syncthreads();
  }
}

// ---------------- Y (bf16 pairs, XOR-swizzled u32 layout) + xb + agg-init ----------------
// Yp[n*1024 + g], g = oh*64 + ((kc^oh)<<2) + r  holds bf16(Y[k*32+2oh]),bf16(Y[k*32+2oh+1]), k=kc*4+r
__global__ __launch_bounds__(256) void k_y2(const float* __restrict__ x,
    const float* __restrict__ We3, const float* __restrict__ be3,
    const float* __restrict__ Wroot, const float* __restrict__ bc1,
    unsigned* __restrict__ Yp, float* __restrict__ xb, float* __restrict__ agg){
  int jb = blockIdx.x & 7;
  int cb = blockIdx.x >> 3;
  int nchunks = gridDim.x >> 3;
  int j = jb*256 + threadIdx.x;   // 0..2047
  int k = j >> 5, o = j & 31;
  int oh = o >> 1, kc = k >> 2, r = k & 3;
  int g = oh*64 + ((kc ^ oh) << 2) + r;
  float w[32];
  #pragma unroll
  for (int f=0;f<32;f++) w[f] = We3[k*1024 + f*32 + o];
  int per = (NN + nchunks - 1)/nchunks;
  int n0 = cb*per;
  int n1 = min(n0+per, NN);
  for (int n=n0;n<n1;n++){
    const float* xr = x + (size_t)n*32;
    float acc = 0.f;
    #pragma unroll
    for (int f=0;f<32;f++) acc += xr[f]*w[f];
    float accB = __shfl_xor(acc, 1);
    if ((o & 1) == 0) Yp[(size_t)n*1024 + g] = pack2(acc, accB);
  }
  if (jb == 0){
    int oo = threadIdx.x & 31;
    int sub = threadIdx.x >> 5;
    float wb[32], wr[32];
    #pragma unroll
    for (int f=0;f<32;f++){ wb[f] = be3[f*32+oo]; wr[f] = Wroot[f*32+oo]; }
    float bcv = bc1[oo];
    for (int n=n0+sub;n<n1;n+=8){
      const float* xr = x + (size_t)n*32;
      float a1 = 0.f, a2 = 0.f;
      #pragma unroll
      for (int f=0;f<32;f++){ float xv = xr[f]; a1 += xv*wb[f]; a2 += xv*wr[f]; }
      xb[(size_t)n*32+oo] = a1;
      agg[(size_t)n*32+oo] = a2 + bcv;
    }
  }
}

// ---------------- msg+aggregate fused: agg[dst] += xb[src] + t2[e]·Yrow(src) ----------------
// wave per src node; t2p rows sequential (CSR order); atomic scatter into agg.
__global__ __launch_bounds__(256) void k_msg2(const unsigned* __restrict__ Yp,
    const float* __restrict__ xb, const float* __restrict__ t2p,
    const int* __restrict__ rp_src, const int* __restrict__ dstp,
    float* __restrict__ agg){
  __shared__ __align__(16) unsigned sY[4][1024];
  __shared__ __align__(16) float sT[4][256];
  int tid=threadIdx.x, w=tid>>6, lane=tid&63;
  int es = lane>>4, l = lane&15;
  int gw = blockIdx.x*4 + w, stride = gridDim.x*4;
  for (int n=gw; n<NN; n+=stride){
    int beg=rp_src[n], end=rp_src[n+1];
    if (beg==end) continue;
    const unsigned* Yr = Yp + (size_t)n*1024;
    #pragma unroll
    for (int q=0;q<4;q++){
      uint4 v = *(const uint4*)(Yr + q*256 + lane*4);
      *(uint4*)(&sY[w][q*256 + lane*4]) = v;
    }
    float2 xbv = *(const float2*)(xb + (size_t)n*32 + 2*l);
    __builtin_amdgcn_wave_barrier();
    for (int pb=beg; pb<end; pb+=4){
      {
        float4 tv = *(const float4*)(t2p + (size_t)pb*64 + lane*4);
        int te = lane>>4, tk = lane&15;
        *(float4*)(&sT[w][(te*16 + (tk^te))*4]) = tv;
      }
      __builtin_amdgcn_wave_barrier();
      float acc0 = xbv.x, acc1 = xbv.y;
      #pragma unroll
      for (int kc=0;kc<16;kc++){
        float4 t = *(const float4*)(&sT[w][(es*16 + (kc^es))*4]);
        uint4 y = *(const uint4*)(&sY[w][(l*16 + (kc^l))*4]);
        acc0 += t.x*__uint_as_float(y.x<<16);
        acc1 += t.x*__uint_as_float(y.x&0xffff0000u);
        acc0 += t.y*__uint_as_float(y.y<<16);
        acc1 += t.y*__uint_as_float(y.y&0xffff0000u);
        acc0 += t.z*__uint_as_float(y.z<<16);
        acc1 += t.z*__uint_as_float(y.z&0xffff0000u);
        acc0 += t.w*__uint_as_float(y.w<<16);
        acc1 += t.w*__uint_as_float(y.w&0xffff0000u);
      }
      int p = pb + es;
      if (p < end){
        int d = dstp[p];
        float* ap = agg + (size_t)d*32 + 2*l;
        unsafeAtomicAdd(ap,   acc0);
        unsafeAtomicAdd(ap+1, acc1);
      }
      __builtin_amdgcn_wave_barrier();
    }
  }
}

// ---------------- column stats (sum, sumsq) for BN; stats pre-zeroed ----------------
__global__ __launch_bounds__(256) void k_stats(const float* __restrict__ buf, int nrows, int ncols,
                                               float* __restrict__ stats){
  int tid = threadIdx.x;
  int c  = tid % ncols;
  int r0 = tid / ncols;
  int rp = 256 / ncols;
  float s1=0.f, s2=0.f;
  for (long long base=(long long)blockIdx.x*rp; base<nrows; base+=(long long)gridDim.x*rp){
    int r = (int)base + r0;
    if (r < nrows){
      float v = buf[(size_t)r*ncols + c];
      s1 += v; s2 += v*v;
    }
  }
  __shared__ float A[256], B[256];
  A[tid]=s1; B[tid]=s2; __syncthreads();
  if (tid < ncols){
    float t1=0.f, t2=0.f;
    for (int gg=0; gg<256/ncols; gg++){ t1 += A[gg*ncols+tid]; t2 += B[gg*ncols+tid]; }
    atomicAdd(&stats[tid], t1);
    atomicAdd(&stats[ncols+tid], t2);
  }
}

// ---------------- GAT linear: in=relu(bn(raw)); hWb=bf16(in@W); sc_s,sc_d ----------------
template<int FIN, int FOUT>
__global__ __launch_bounds__(256) void k_gat_linear(const float* __restrict__ raw,
    const float* __restrict__ stats, const float* __restrict__ W,
    const float* __restrict__ avs, const float* __restrict__ avd,
    unsigned short* __restrict__ hWb, float* __restrict__ sc_s, float* __restrict__ sc_d){
  __shared__ float sW[FIN*FOUT];
  __shared__ float sA[FOUT], sD[FOUT];
  __shared__ float sScale[FIN], sShift[FIN];
  __shared__ float sIn[4][FIN];
  int tid = threadIdx.x;
  for (int i=tid;i<FIN*FOUT;i+=256) sW[i]=W[i];
  if (tid<FOUT){ sA[tid]=avs[tid]; sD[tid]=avd[tid]; }
  if (tid<FIN){
    float m = stats[tid]*(1.f/NN);
    float v = stats[FIN+tid]*(1.f/NN) - m*m;
    float s = rsqrtf(v + 1e-5f);
    sScale[tid]=s; sShift[tid]=-m*s;
  }
  __syncthreads();
  int wave=tid>>6, lane=tid&63;
  for (int nb = blockIdx.x*4; nb < NN; nb += gridDim.x*4){
    int n = nb + wave;
    bool act = n < NN;
    if (act){
      for (int ff=lane; ff<FIN; ff+=64){
        float vv = raw[(size_t)n*FIN+ff]*sScale[ff]+sShift[ff];
        sIn[wave][ff] = fmaxf(vv, 0.f);
      }
    }
    __syncthreads();
    if (act){
      float out0=0.f, out1=0.f;
      #pragma unroll
      for (int ff=0; ff<FIN; ff++){
        float xv = sIn[wave][ff];
        out0 += xv*sW[ff*FOUT+lane];
        if constexpr (FOUT > 64) out1 += xv*sW[ff*FOUT+lane+64];
      }
      hWb[(size_t)n*FOUT + lane] = f2bf(out0);
      float ps = out0*sA[lane], pd = out0*sD[lane];
      if constexpr (FOUT > 64){
        hWb[(size_t)n*FOUT + lane + 64] = f2bf(out1);
        ps += out1*sA[lane+64]; pd += out1*sD[lane+64];
      }
      #pragma unroll
      for (int off=32;off>0;off>>=1){ ps += __shfl_down(ps,off); pd += __shfl_down(pd,off); }
      if (lane==0){ sc_s[n]=ps; sc_d[n]=pd; }
    }
    __syncthreads();
  }
}

// ---------------- GAT attention: single pass, online softmax, bf16 gathers ----------------
template<int F>
__global__ __launch_bounds__(256) void k_gat_attn2(const unsigned short* __restrict__ hWb,
    const float* __restrict__ sc_s, const float* __restrict__ sc_d,
    const int* __restrict__ rp_dst, const int* __restrict__ srcd,
    const float* __restrict__ bias, float* __restrict__ outraw){
  __shared__ float sp[4][64];
  __shared__ int ssi[4][64];
  int tid=threadIdx.x, w=tid>>6, lane=tid&63;
  int gw = blockIdx.x*4 + w, stride = gridDim.x*4;
  for (int n=gw; n<NN; n+=stride){
    int beg=rp_dst[n], end=rp_dst[n+1];
    float scd = sc_d[n];
    float M=-3e38f, S=0.f, acc0=0.f, acc1=0.f;
    for (int base=beg; base<end; base+=64){
      int nb = min(64, end-base);
      int si=0; float sc=-3e38f;
      if (lane<nb){ si = srcd[base+lane]; sc = lrelu(sc_s[si]+scd); }
      float cm=sc;
      #pragma unroll
      for (int off=32;off>0;off>>=1) cm = fmaxf(cm, __shfl_xor(cm,off));
      float Mn = fmaxf(M, cm);
      float p = (lane<nb) ? __expf(sc-Mn) : 0.f;
      float ps=p;
      #pragma unroll
      for (int off=32;off>0;off>>=1) ps += __shfl_xor(ps,off);
      float scale = __expf(M-Mn);
      S = S*scale + ps;
      acc0*=scale; acc1*=scale;
      sp[w][lane]=p; ssi[w][lane]=si;
      __builtin_amdgcn_wave_barrier();
      for (int jj=0;jj<nb;jj++){
        float pj = sp[w][jj]; int sj = ssi[w][jj];
        if constexpr (F==128){
          unsigned u = *(const unsigned*)(hWb + (size_t)sj*128 + 2*lane);
          acc0 += pj*__uint_as_float(u<<16);
          acc1 += pj*__uint_as_float(u&0xffff0000u);
        } else {
          acc0 += pj*__uint_as_float(((unsigned)hWb[(size_t)sj*64+lane])<<16);
        }
      }
      __builtin_amdgcn_wave_barrier();
      M = Mn;
    }
    float sself = lrelu(sc_s[n]+scd);
    float Mn = fmaxf(M, sself);
    float scale = __expf(M-Mn);
    float pself = __expf(sself-Mn);
    S = S*scale + pself;
    acc0*=scale; acc1*=scale;
    float inv;
    if constexpr (F==128){
      unsigned u = *(const unsigned*)(hWb + (size_t)n*128 + 2*lane);
      acc0 += pself*__uint_as_float(u<<16);
      acc1 += pself*__uint_as_float(u&0xffff0000u);
      inv = 1.f/(S+1e-16f);
      float2 ov;
      ov.x = acc0*inv + bias[2*lane];
      ov.y = acc1*inv + bias[2*lane+1];
      *(float2*)(outraw + (size_t)n*128 + 2*lane) = ov;
    } else {
      acc0 += pself*__uint_as_float(((unsigned)hWb[(size_t)n*64+lane])<<16);
      inv = 1.f/(S+1e-16f);
      outraw[(size_t)n*64+lane] = acc0*inv + bias[lane];
    }
  }
}

// ---------------- mean pool with bn+relu on read ----------------
__global__ __launch_bounds__(256) void k_pool(const float* __restrict__ h2raw,
    const float* __restrict__ stats, const int* __restrict__ starts,
    float* __restrict__ g){
  __shared__ float sc[128], sh[128];
  __shared__ float red[256];
  int b=blockIdx.x, t=threadIdx.x;
  if (t<128){
    float m = stats[t]*(1.f/NN);
    float v = stats[128+t]*(1.f/NN) - m*m;
    float s = rsqrtf(v+1e-5f);
    sc[t]=s; sh[t]=-m*s;
  }
  __syncthreads();
  int s0=starts[b], s1=starts[b+1];
  int f=t&127, half=t>>7;
  float acc=0.f;
  for (int n=s0+half;n<s1;n+=2){
    float v = h2raw[(size_t)n*128+f]*sc[f]+sh[f];
    acc += fmaxf(v,0.f);
  }
  red[t]=acc; __syncthreads();
  if (half==0){
    int cnt = s1-s0;
    g[b*128+f] = (red[f]+red[128+f]) / fmaxf((float)cnt, 1.f);
  }
}

// ---------------- FC head ----------------
__global__ __launch_bounds__(256) void k_head1(const float* __restrict__ g,
    const float* __restrict__ Wf1, const float* __restrict__ bf1, float* __restrict__ g1){
  __shared__ float sg[128];
  int r=blockIdx.x, t=threadIdx.x;
  if (t<128) sg[t]=g[r*128+t];
  __syncthreads();
  float acc=bf1[t];
  #pragma unroll 4
  for (int k=0;k<128;k++) acc += sg[k]*Wf1[k*256+t];
  g1[r*256+t]=acc;
}

__global__ __launch_bounds__(256) void k_head2(const float* __restrict__ g1,
    const float* __restrict__ stats, const float* __restrict__ Wf2,
    const float* __restrict__ bf2, float* __restrict__ g2){
  __shared__ float sin_[256];
  int r=blockIdx.x, t=threadIdx.x;
  float m = stats[t]*(1.f/NGB);
  float v = stats[256+t]*(1.f/NGB) - m*m;
  float val = (g1[r*256+t]-m)*rsqrtf(v+1e-5f);
  sin_[t]=fmaxf(val,0.f);
  __syncthreads();
  if (t<128){
    float acc=bf2[t];
    #pragma unroll 4
    for (int k=0;k<256;k++) acc += sin_[k]*Wf2[k*128+t];
    g2[r*128+t]=acc;
  }
}

__global__ __launch_bounds__(256) void k_head3(const float* __restrict__ g2,
    const float* __restrict__ stats, const float* __restrict__ Wf3,
    const float* __restrict__ bf3, float* __restrict__ out){
  __shared__ float sin_[128];
  int r=blockIdx.x, t=threadIdx.x;
  if (t<128){
    float m = stats[t]*(1.f/NGB);
    float v = stats[128+t]*(1.f/NGB) - m*m;
    float val = (g2[r*128+t]-m)*rsqrtf(v+1e-5f);
    sin_[t]=fmaxf(val,0.f);
  }
  __syncthreads();
  if (t<64){
    float acc=bf3[t];
    #pragma unroll 4
    for (int k=0;k<128;k++) acc += sin_[k]*Wf3[k*64+t];
    out[r*64+t]=acc;
  }
}

extern "C" void kernel_launch(void* const* d_in, const int* in_sizes, int n_in,
                              void* d_out, int out_size, void* d_ws, size_t ws_size,
                              hipStream_t stream){
  const float* x    = (const float*)d_in[0];
  const int*   ei   = (const int*)d_in[1];
  const float* ea   = (const float*)d_in[2];
  const int*   batch= (const int*)d_in[3];
  const float* We1=(const float*)d_in[4];  const float* be1=(const float*)d_in[5];
  const float* We2=(const float*)d_in[6];  const float* be2=(const float*)d_in[7];
  const float* We3=(const float*)d_in[8];  const float* be3=(const float*)d_in[9];
  const float* Wroot=(const float*)d_in[10]; const float* bc1=(const float*)d_in[11];
  const float* Wg1=(const float*)d_in[12]; const float* as1=(const float*)d_in[13];
  const float* ad1=(const float*)d_in[14]; const float* bg1=(const float*)d_in[15];
  const float* Wg2=(const float*)d_in[16]; const float* as2=(const float*)d_in[17];
  const float* ad2=(const float*)d_in[18]; const float* bg2=(const float*)d_in[19];
  const float* Wf1=(const float*)d_in[20]; const float* bf1=(const float*)d_in[21];
  const float* Wf2=(const float*)d_in[22]; const float* bf2=(const float*)d_in[23];
  const float* Wf3=(const float*)d_in[24]; const float* bf3=(const float*)d_in[25];
  (void)in_sizes; (void)n_in; (void)out_size; (void)ws_size;
  float* out = (float*)d_out;
  char* ws = (char*)d_ws;
  const int* srcA = ei;
  const int* dstA = ei + NE;

  size_t off = 0;
  auto take = [&](size_t bytes)->size_t{ size_t r = off; off += (bytes + 255) & ~(size_t)255; return r; };
  // zero region
  size_t o_deg_src = take(NN*4), o_deg_dst = take(NN*4);
  size_t o_fill_src = take(NN*4), o_fill_dst = take(NN*4);
  size_t o_stats0 = take(2*32*4), o_stats1 = take(2*64*4), o_stats2 = take(2*128*4);
  size_t o_statsH1 = take(2*256*4), o_statsH2 = take(2*128*4);
  size_t zero_bytes = off;
  // rest
  size_t o_rp_src = take((NN+1)*4), o_rp_dst = take((NN+1)*4);
  size_t o_pos_src = take((size_t)NE*4);
  size_t o_dstp = take((size_t)NE*4);
  size_t o_srcd = take((size_t)NE*4);
  size_t o_starts = take((NGB+1)*4);
  size_t o_W1p = take(4096*2);
  size_t o_W2p = take(8192*2);
  size_t o_t2p = take((size_t)(NE+8)*64*4);
  size_t o_Yp  = take((size_t)NN*1024*4);
  size_t o_xb  = take((size_t)NN*32*4);
  size_t o_agg = take((size_t)NN*32*4);
  size_t o_hW1b = take((size_t)NN*64*2);
  size_t o_scs1 = take(NN*4), o_scd1 = take(NN*4);
  size_t o_h1  = take((size_t)NN*64*4);
  size_t o_hW2b = take((size_t)NN*128*2);
  size_t o_scs2 = take(NN*4), o_scd2 = take(NN*4);
  size_t o_h2  = take((size_t)NN*128*4);
  size_t o_g   = take(NGB*128*4);
  size_t o_g1  = take(NGB*256*4);
  size_t o_g2  = take(NGB*128*4);

  #define WF(o) ((float*)(ws + (o)))
  #define WI(o) ((int*)(ws + (o)))
  #define WU(o) ((unsigned short*)(ws + (o)))
  #define WW(o) ((unsigned*)(ws + (o)))

  hipMemsetAsync(ws, 0, zero_bytes, stream);
  k_degrees<<<(NE+255)/256,256,0,stream>>>(srcA,dstA,WI(o_deg_src),WI(o_deg_dst));
  k_scan<<<2,1024,0,stream>>>(WI(o_deg_src),WI(o_deg_dst),WI(o_rp_src),WI(o_rp_dst));
  k_fill<<<(NE+255)/256,256,0,stream>>>(srcA,dstA,WI(o_rp_src),WI(o_rp_dst),
                                        WI(o_fill_src),WI(o_fill_dst),
                                        WI(o_pos_src),WI(o_dstp),WI(o_srcd));
  k_bounds<<<(NN+256)/256,256,0,stream>>>(batch,WI(o_starts));

  k_pack<<<1,256,0,stream>>>(We1,be1,We2,WU(o_W1p),WU(o_W2p));
  k_edge_mlp2<<<500,256,0,stream>>>(ea,WU(o_W1p),WU(o_W2p),be2,WI(o_pos_src),WF(o_t2p));
  k_y2<<<512,256,0,stream>>>(x,We3,be3,Wroot,bc1,WW(o_Yp),WF(o_xb),WF(o_agg));
  k_msg2<<<1250,256,0,stream>>>(WW(o_Yp),WF(o_xb),WF(o_t2p),WI(o_rp_src),WI(o_dstp),WF(o_agg));

  k_stats<<<64,256,0,stream>>>(WF(o_agg),NN,32,WF(o_stats0));
  k_gat_linear<32,64><<<640,256,0,stream>>>(WF(o_agg),WF(o_stats0),Wg1,as1,ad1,
                                            WU(o_hW1b),WF(o_scs1),WF(o_scd1));
  k_gat_attn2<64><<<640,256,0,stream>>>(WU(o_hW1b),WF(o_scs1),WF(o_scd1),
                                        WI(o_rp_dst),WI(o_srcd),bg1,WF(o_h1));
  k_stats<<<64,256,0,stream>>>(WF(o_h1),NN,64,WF(o_stats1));
  k_gat_linear<64,128><<<640,256,0,stream>>>(WF(o_h1),WF(o_stats1),Wg2,as2,ad2,
                                             WU(o_hW2b),WF(o_scs2),WF(o_scd2));
  k_gat_attn2<128><<<640,256,0,stream>>>(WU(o_hW2b),WF(o_scs2),WF(o_scd2),
                                         WI(o_rp_dst),WI(o_srcd),bg2,WF(o_h2));
  k_stats<<<64,256,0,stream>>>(WF(o_h2),NN,128,WF(o_stats2));

  k_pool<<<NGB,256,0,stream>>>(WF(o_h2),WF(o_stats2),WI(o_starts),WF(o_g));
  k_head1<<<NGB,256,0,stream>>>(WF(o_g),Wf1,bf1,WF(o_g1));
  k_stats<<<64,256,0,stream>>>(WF(o_g1),NGB,256,WF(o_statsH1));
  k_head2<<<NGB,256,0,stream>>>(WF(o_g1),WF(o_statsH1),Wf2,bf2,WF(o_g2));
  k_stats<<<64,256,0,stream>>>(WF(o_g2),NGB,128,WF(o_statsH2));
  k_head3<<<NGB,256,0,stream>>>(WF(o_g2),WF(o_statsH2),Wf3,bf3,out);
}

// Round 4
// 374.595 us; speedup vs baseline: 1.6620x; 1.0569x over previous
//
#include <hip/hip_runtime.h>

#define NN 10000      // nodes
#define NE 160000     // edges
#define NGB 100       // graphs

typedef __attribute__((ext_vector_type(8))) short s8v;   // 8 x bf16 (4 VGPR)
typedef __attribute__((ext_vector_type(4))) float f4v;   // MFMA accumulator

static __device__ __forceinline__ float lrelu(float v){ return v > 0.f ? v : 0.2f*v; }
static __device__ __forceinline__ unsigned short f2bf(float f){
  unsigned u = __float_as_uint(f);
  u += 0x7fffu + ((u >> 16) & 1u);
  return (unsigned short)(u >> 16);
}
static __device__ __forceinline__ unsigned pack2(float a, float b){
  return (unsigned)f2bf(a) | ((unsigned)f2bf(b) << 16);
}

// ---------------- CSR build ----------------
__global__ __launch_bounds__(256) void k_degrees(const int* __restrict__ src, const int* __restrict__ dst,
                                                 int* deg_src, int* deg_dst){
  int i = blockIdx.x*256 + threadIdx.x;
  if (i < NE){ atomicAdd(&deg_src[src[i]],1); atomicAdd(&deg_dst[dst[i]],1); }
}

__global__ __launch_bounds__(1024) void k_scan(const int* __restrict__ deg_src, const int* __restrict__ deg_dst,
                                               int* rp_src, int* rp_dst){
  const int* deg = (blockIdx.x==0) ? deg_src : deg_dst;
  int* rp = (blockIdx.x==0) ? rp_src : rp_dst;
  __shared__ int part[1024];
  int tid = threadIdx.x;
  const int per = (NN + 1023)/1024;   // 10
  int base = tid*per;
  int s = 0;
  for (int i=0;i<per;i++){ int idx=base+i; if (idx<NN) s += deg[idx]; }
  part[tid]=s; __syncthreads();
  for (int off=1; off<1024; off<<=1){
    int v = part[tid];
    int add = (tid>=off) ? part[tid-off] : 0;
    __syncthreads();
    part[tid] = v + add;
    __syncthreads();
  }
  int run = (tid==0) ? 0 : part[tid-1];
  for (int i=0;i<per;i++){ int idx=base+i; if (idx<NN){ rp[idx]=run; run += deg[idx]; } }
  if (tid==1023) rp[NN] = part[1023];
}

// pos_src[e]: slot of edge e in CSR-src order; dstp[p]=dst of edge at src-slot p;
// srcd[q]=src of edge at dst-slot q.
__global__ __launch_bounds__(256) void k_fill(const int* __restrict__ src, const int* __restrict__ dst,
                       const int* __restrict__ rp_src, const int* __restrict__ rp_dst,
                       int* fill_src, int* fill_dst, int* pos_src, int* dstp, int* srcd){
  int i = blockIdx.x*256 + threadIdx.x;
  if (i < NE){
    int s=src[i], d=dst[i];
    int p=rp_src[s]+atomicAdd(&fill_src[s],1); pos_src[i]=p; dstp[p]=d;
    int q=rp_dst[d]+atomicAdd(&fill_dst[d],1); srcd[q]=s;
  }
}

__global__ __launch_bounds__(256) void k_bounds(const int* __restrict__ batch, int* starts){
  int n = blockIdx.x*256 + threadIdx.x;
  if (n > NN) return;
  int cur  = (n==NN) ? NGB : batch[n];
  int prev = (n==0)  ? -1  : batch[n-1];
  for (int b=prev+1; b<=cur; b++) if (b<=NGB) starts[b]=n;
}

// ---------------- weight pack for MFMA edge MLP ----------------
__global__ __launch_bounds__(256) void k_pack(const float* __restrict__ We1, const float* __restrict__ be1,
    const float* __restrict__ We2, unsigned short* __restrict__ W1p, unsigned short* __restrict__ W2p){
  int tid = threadIdx.x;
  for (int idx=tid; idx<512; idx+=256){
    int j=idx>>6, l=idx&63, col=l&15, g=l>>4;
    int out = j*16+col;
    #pragma unroll
    for (int jj=0;jj<8;jj++){
      int k = g*8+jj;
      float v = (k<16) ? We1[k*128+out] : (k==16 ? be1[out] : 0.f);
      W1p[idx*8+jj] = f2bf(v);
    }
  }
  for (int idx=tid; idx<1024; idx+=256){
    int ft=idx>>6, l=idx&63, col=l&15, g=l>>4;
    int t=ft>>2, jo=ft&3;
    int out = jo*16+col;
    #pragma unroll
    for (int jj=0;jj<8;jj++){
      int k = t*32+g*8+jj;
      W2p[idx*8+jj] = f2bf(We2[k*64+out]);
    }
  }
}

// ---------------- EdgeMLP via MFMA -> t2 rows scattered into CSR-src order ----------------
__global__ __launch_bounds__(256) void k_edge_mlp2(const float* __restrict__ ea,
    const unsigned short* __restrict__ W1p, const unsigned short* __restrict__ W2p,
    const float* __restrict__ be2, const int* __restrict__ pos_src, float* __restrict__ t2p){
  __shared__ unsigned short st1[4*2048];   // [wave][16 edges][128 k] bf16, XOR-swizzled
  int tid=threadIdx.x, wave=tid>>6, lane=tid&63;
  int c = lane&15, g = lane>>4;
  s8v w1f[8], w2f[16];
  #pragma unroll
  for (int j=0;j<8;j++)  w1f[j] = *(const s8v*)(W1p + (size_t)(j*64+lane)*8);
  #pragma unroll
  for (int q=0;q<16;q++) w2f[q] = *(const s8v*)(W2p + (size_t)(q*64+lane)*8);
  float be2v[16];
  #pragma unroll
  for (int jo=0;jo<4;jo++)
    #pragma unroll
    for (int r=0;r<4;r++) be2v[jo*4+r] = be2[jo*16+g*4+r];
  char* myld = (char*)(st1 + wave*2048);
  const f4v fzero = {0.f,0.f,0.f,0.f};

  for (int base = blockIdx.x*64; base < NE; base += gridDim.x*64){
    int e0 = base + wave*16;
    s8v eaf = {0,0,0,0,0,0,0,0};
    if (g < 2){
      const float* p = ea + (size_t)(e0+c)*16 + g*8;
      float4 a = *(const float4*)p;
      float4 b = *(const float4*)(p+4);
      eaf[0]=(short)f2bf(a.x); eaf[1]=(short)f2bf(a.y); eaf[2]=(short)f2bf(a.z); eaf[3]=(short)f2bf(a.w);
      eaf[4]=(short)f2bf(b.x); eaf[5]=(short)f2bf(b.y); eaf[6]=(short)f2bf(b.z); eaf[7]=(short)f2bf(b.w);
    } else if (g == 2){
      eaf[0] = (short)0x3f80;  // bf16(1.0) bias slot
    }
    f4v acc1[8];
    #pragma unroll
    for (int j=0;j<8;j++)
      acc1[j] = __builtin_amdgcn_mfma_f32_16x16x32_bf16(w1f[j], eaf, fzero, 0, 0, 0);
    #pragma unroll
    for (int j=0;j<8;j++){
      unsigned lo = pack2(fmaxf(acc1[j][0],0.f), fmaxf(acc1[j][1],0.f));
      unsigned hi = pack2(fmaxf(acc1[j][2],0.f), fmaxf(acc1[j][3],0.f));
      unsigned off = (unsigned)(c*256 + ((j*32 + g*8) ^ (c<<4)));
      *(uint2*)(myld + off) = make_uint2(lo, hi);
    }
    __syncthreads();
    f4v acc2[4];
    #pragma unroll
    for (int jo=0;jo<4;jo++) acc2[jo] = fzero;
    #pragma unroll
    for (int t=0;t<4;t++){
      unsigned off = (unsigned)(c*256 + ((t*64 + g*16) ^ (c<<4)));
      s8v b2 = *(const s8v*)(myld + off);
      #pragma unroll
      for (int jo=0;jo<4;jo++)
        acc2[jo] = __builtin_amdgcn_mfma_f32_16x16x32_bf16(w2f[t*4+jo], b2, acc2[jo], 0, 0, 0);
    }
    int pos = pos_src[e0+c];
    float* orow = t2p + (size_t)pos*64;
    #pragma unroll
    for (int jo=0;jo<4;jo++){
      f4v v;
      #pragma unroll
      for (int r=0;r<4;r++) v[r] = fmaxf(acc2[jo][r] + be2v[jo*4+r], 0.f);
      *(f4v*)(orow + jo*16 + g*4) = v;
    }
    __syncthreads();
  }
}

// ---------------- Y (bf16 pairs, XOR-swizzled u32 layout), GEMM-style ----------------
// thread owns u32-pair m = jb*256+tid: oh=m>>6 (o=2oh,2oh+1), k=m&63.
// 8 x-rows staged in LDS per iter; write at swizzled index (coalesced within 256B).
__global__ __launch_bounds__(256) void k_y3(const float* __restrict__ x,
    const float* __restrict__ We3, unsigned* __restrict__ Yp){
  __shared__ __align__(16) float sx[8][32];
  int jb = blockIdx.x & 3;
  int cb = blockIdx.x >> 2;
  int nch = gridDim.x >> 2;
  int m = jb*256 + threadIdx.x;
  int oh = m >> 6, k = m & 63, kc = k >> 2, r = k & 3;
  unsigned gsw = (unsigned)((oh<<6) | (((kc ^ oh) & 15) << 2) | r);
  float w0[32], w1[32];
  #pragma unroll
  for (int f=0; f<32; f++){
    float2 wv = *(const float2*)(We3 + (size_t)k*1024 + f*32 + 2*oh);
    w0[f] = wv.x; w1[f] = wv.y;
  }
  int per = (1250 + nch - 1)/nch;        // node groups of 8 (NN/8 = 1250)
  int g0 = cb*per, g1 = min(g0+per, 1250);
  for (int gi=g0; gi<g1; gi++){
    int nb = gi*8;
    __syncthreads();
    sx[threadIdx.x>>5][threadIdx.x&31] = x[(size_t)nb*32 + threadIdx.x];
    __syncthreads();
    #pragma unroll
    for (int nn=0; nn<8; nn++){
      float a0=0.f, a1=0.f;
      #pragma unroll
      for (int f4=0; f4<8; f4++){
        float4 xv = *(const float4*)(&sx[nn][f4*4]);
        a0 += xv.x*w0[f4*4+0] + xv.y*w0[f4*4+1] + xv.z*w0[f4*4+2] + xv.w*w0[f4*4+3];
        a1 += xv.x*w1[f4*4+0] + xv.y*w1[f4*4+1] + xv.z*w1[f4*4+2] + xv.w*w1[f4*4+3];
      }
      Yp[(size_t)(nb+nn)*1024 + gsw] = pack2(a0, a1);
    }
  }
}

// ---------------- xb[n,o] = x@be3-fold ; agg-init = x@Wroot + bc1 ----------------
__global__ __launch_bounds__(256) void k_xbagg(const float* __restrict__ x,
    const float* __restrict__ be3, const float* __restrict__ Wroot, const float* __restrict__ bc1,
    float* __restrict__ xb, float* __restrict__ agg){
  __shared__ __align__(16) float sx[8][32];
  int oo = threadIdx.x & 31, nn = threadIdx.x >> 5;
  float wb[32], wr[32];
  #pragma unroll
  for (int f=0;f<32;f++){ wb[f]=be3[f*32+oo]; wr[f]=Wroot[f*32+oo]; }
  float bcv = bc1[oo];
  int per = (1250 + gridDim.x - 1)/gridDim.x;
  int g0 = blockIdx.x*per, g1 = min(g0+per, 1250);
  for (int gi=g0; gi<g1; gi++){
    int nb = gi*8;
    __syncthreads();
    sx[threadIdx.x>>5][threadIdx.x&31] = x[(size_t)nb*32 + threadIdx.x];
    __syncthreads();
    float a1=0.f, a2=0.f;
    #pragma unroll
    for (int f4=0;f4<8;f4++){
      float4 xv = *(const float4*)(&sx[nn][f4*4]);
      a1 += xv.x*wb[f4*4+0]+xv.y*wb[f4*4+1]+xv.z*wb[f4*4+2]+xv.w*wb[f4*4+3];
      a2 += xv.x*wr[f4*4+0]+xv.y*wr[f4*4+1]+xv.z*wr[f4*4+2]+xv.w*wr[f4*4+3];
    }
    xb[(size_t)(nb+nn)*32+oo] = a1;
    agg[(size_t)(nb+nn)*32+oo] = a2 + bcv;
  }
}

// ---------------- msg+aggregate fused: agg[dst] += xb[src] + t2[e]·Yrow(src) ----------------
__global__ __launch_bounds__(256) void k_msg2(const unsigned* __restrict__ Yp,
    const float* __restrict__ xb, const float* __restrict__ t2p,
    const int* __restrict__ rp_src, const int* __restrict__ dstp,
    float* __restrict__ agg){
  __shared__ __align__(16) unsigned sY[4][1024];
  __shared__ __align__(16) float sT[4][256];
  int tid=threadIdx.x, w=tid>>6, lane=tid&63;
  int es = lane>>4, l = lane&15;
  int gw = blockIdx.x*4 + w, stride = gridDim.x*4;
  for (int n=gw; n<NN; n+=stride){
    int beg=rp_src[n], end=rp_src[n+1];
    if (beg==end) continue;
    const unsigned* Yr = Yp + (size_t)n*1024;
    #pragma unroll
    for (int q=0;q<4;q++){
      uint4 v = *(const uint4*)(Yr + q*256 + lane*4);
      *(uint4*)(&sY[w][q*256 + lane*4]) = v;
    }
    float2 xbv = *(const float2*)(xb + (size_t)n*32 + 2*l);
    __builtin_amdgcn_wave_barrier();
    for (int pb=beg; pb<end; pb+=4){
      {
        float4 tv = *(const float4*)(t2p + (size_t)pb*64 + lane*4);
        int te = lane>>4, tk = lane&15;
        *(float4*)(&sT[w][(te*16 + (tk^te))*4]) = tv;
      }
      __builtin_amdgcn_wave_barrier();
      float acc0 = xbv.x, acc1 = xbv.y;
      #pragma unroll
      for (int kc=0;kc<16;kc++){
        float4 t = *(const float4*)(&sT[w][(es*16 + (kc^es))*4]);
        uint4 y = *(const uint4*)(&sY[w][(l*16 + (kc^l))*4]);
        acc0 += t.x*__uint_as_float(y.x<<16);
        acc1 += t.x*__uint_as_float(y.x&0xffff0000u);
        acc0 += t.y*__uint_as_float(y.y<<16);
        acc1 += t.y*__uint_as_float(y.y&0xffff0000u);
        acc0 += t.z*__uint_as_float(y.z<<16);
        acc1 += t.z*__uint_as_float(y.z&0xffff0000u);
        acc0 += t.w*__uint_as_float(y.w<<16);
        acc1 += t.w*__uint_as_float(y.w&0xffff0000u);
      }
      int p = pb + es;
      if (p < end){
        int d = dstp[p];
        float* ap = agg + (size_t)d*32 + 2*l;
        unsafeAtomicAdd(ap,   acc0);
        unsafeAtomicAdd(ap+1, acc1);
      }
      __builtin_amdgcn_wave_barrier();
    }
  }
}

// ---------------- column stats (sum, sumsq) for BN; stats pre-zeroed ----------------
__global__ __launch_bounds__(256) void k_stats(const float* __restrict__ buf, int nrows, int ncols,
                                               float* __restrict__ stats){
  int tid = threadIdx.x;
  int c  = tid % ncols;
  int r0 = tid / ncols;
  int rp = 256 / ncols;
  float s1=0.f, s2=0.f;
  for (long long base=(long long)blockIdx.x*rp; base<nrows; base+=(long long)gridDim.x*rp){
    int r = (int)base + r0;
    if (r < nrows){
      float v = buf[(size_t)r*ncols + c];
      s1 += v; s2 += v*v;
    }
  }
  __shared__ float A[256], B[256];
  A[tid]=s1; B[tid]=s2; __syncthreads();
  if (tid < ncols){
    float t1=0.f, t2=0.f;
    for (int gg=0; gg<256/ncols; gg++){ t1 += A[gg*ncols+tid]; t2 += B[gg*ncols+tid]; }
    atomicAdd(&stats[tid], t1);
    atomicAdd(&stats[ncols+tid], t2);
  }
}

// ---------------- GAT linear: in=relu(bn(raw)); hWb=bf16(in@W); sc_s,sc_d ----------------
template<int FIN, int FOUT>
__global__ __launch_bounds__(256) void k_gat_linear(const float* __restrict__ raw,
    const float* __restrict__ stats, const float* __restrict__ W,
    const float* __restrict__ avs, const float* __restrict__ avd,
    unsigned short* __restrict__ hWb, float* __restrict__ sc_s, float* __restrict__ sc_d){
  __shared__ float sW[FIN*FOUT];
  __shared__ float sA[FOUT], sD[FOUT];
  __shared__ float sScale[FIN], sShift[FIN];
  __shared__ float sIn[4][FIN];
  int tid = threadIdx.x;
  for (int i=tid;i<FIN*FOUT;i+=256) sW[i]=W[i];
  if (tid<FOUT){ sA[tid]=avs[tid]; sD[tid]=avd[tid]; }
  if (tid<FIN){
    float m = stats[tid]*(1.f/NN);
    float v = stats[FIN+tid]*(1.f/NN) - m*m;
    float s = rsqrtf(v + 1e-5f);
    sScale[tid]=s; sShift[tid]=-m*s;
  }
  __syncthreads();
  int wave=tid>>6, lane=tid&63;
  for (int nb = blockIdx.x*4; nb < NN; nb += gridDim.x*4){
    int n = nb + wave;
    bool act = n < NN;
    if (act){
      for (int ff=lane; ff<FIN; ff+=64){
        float vv = raw[(size_t)n*FIN+ff]*sScale[ff]+sShift[ff];
        sIn[wave][ff] = fmaxf(vv, 0.f);
      }
    }
    __syncthreads();
    if (act){
      float out0=0.f, out1=0.f;
      #pragma unroll
      for (int ff=0; ff<FIN; ff++){
        float xv = sIn[wave][ff];
        out0 += xv*sW[ff*FOUT+lane];
        if constexpr (FOUT > 64) out1 += xv*sW[ff*FOUT+lane+64];
      }
      hWb[(size_t)n*FOUT + lane] = f2bf(out0);
      float ps = out0*sA[lane], pd = out0*sD[lane];
      if constexpr (FOUT > 64){
        hWb[(size_t)n*FOUT + lane + 64] = f2bf(out1);
        ps += out1*sA[lane+64]; pd += out1*sD[lane+64];
      }
      #pragma unroll
      for (int off=32;off>0;off>>=1){ ps += __shfl_down(ps,off); pd += __shfl_down(pd,off); }
      if (lane==0){ sc_s[n]=ps; sc_d[n]=pd; }
    }
    __syncthreads();
  }
}

// ---------------- GAT attention: single pass, online softmax, bf16 gathers ----------------
template<int F>
__global__ __launch_bounds__(256) void k_gat_attn2(const unsigned short* __restrict__ hWb,
    const float* __restrict__ sc_s, const float* __restrict__ sc_d,
    const int* __restrict__ rp_dst, const int* __restrict__ srcd,
    const float* __restrict__ bias, float* __restrict__ outraw){
  __shared__ float sp[4][64];
  __shared__ int ssi[4][64];
  int tid=threadIdx.x, w=tid>>6, lane=tid&63;
  int gw = blockIdx.x*4 + w, stride = gridDim.x*4;
  for (int n=gw; n<NN; n+=stride){
    int beg=rp_dst[n], end=rp_dst[n+1];
    float scd = sc_d[n];
    float M=-3e38f, S=0.f, acc0=0.f, acc1=0.f;
    for (int base=beg; base<end; base+=64){
      int nb = min(64, end-base);
      int si=0; float sc=-3e38f;
      if (lane<nb){ si = srcd[base+lane]; sc = lrelu(sc_s[si]+scd); }
      float cm=sc;
      #pragma unroll
      for (int off=32;off>0;off>>=1) cm = fmaxf(cm, __shfl_xor(cm,off));
      float Mn = fmaxf(M, cm);
      float p = (lane<nb) ? __expf(sc-Mn) : 0.f;
      float ps=p;
      #pragma unroll
      for (int off=32;off>0;off>>=1) ps += __shfl_xor(ps,off);
      float scale = __expf(M-Mn);
      S = S*scale + ps;
      acc0*=scale; acc1*=scale;
      sp[w][lane]=p; ssi[w][lane]=si;
      __builtin_amdgcn_wave_barrier();
      for (int jj=0;jj<nb;jj++){
        float pj = sp[w][jj]; int sj = ssi[w][jj];
        if constexpr (F==128){
          unsigned u = *(const unsigned*)(hWb + (size_t)sj*128 + 2*lane);
          acc0 += pj*__uint_as_float(u<<16);
          acc1 += pj*__uint_as_float(u&0xffff0000u);
        } else {
          acc0 += pj*__uint_as_float(((unsigned)hWb[(size_t)sj*64+lane])<<16);
        }
      }
      __builtin_amdgcn_wave_barrier();
      M = Mn;
    }
    float sself = lrelu(sc_s[n]+scd);
    float Mn = fmaxf(M, sself);
    float scale = __expf(M-Mn);
    float pself = __expf(sself-Mn);
    S = S*scale + pself;
    acc0*=scale; acc1*=scale;
    float inv;
    if constexpr (F==128){
      unsigned u = *(const unsigned*)(hWb + (size_t)n*128 + 2*lane);
      acc0 += pself*__uint_as_float(u<<16);
      acc1 += pself*__uint_as_float(u&0xffff0000u);
      inv = 1.f/(S+1e-16f);
      float2 ov;
      ov.x = acc0*inv + bias[2*lane];
      ov.y = acc1*inv + bias[2*lane+1];
      *(float2*)(outraw + (size_t)n*128 + 2*lane) = ov;
    } else {
      acc0 += pself*__uint_as_float(((unsigned)hWb[(size_t)n*64+lane])<<16);
      inv = 1.f/(S+1e-16f);
      outraw[(size_t)n*64+lane] = acc0*inv + bias[lane];
    }
  }
}

// ---------------- mean pool with bn+relu on read ----------------
__global__ __launch_bounds__(256) void k_pool(const float* __restrict__ h2raw,
    const float* __restrict__ stats, const int* __restrict__ starts,
    float* __restrict__ g){
  __shared__ float sc[128], sh[128];
  __shared__ float red[256];
  int b=blockIdx.x, t=threadIdx.x;
  if (t<128){
    float m = stats[t]*(1.f/NN);
    float v = stats[128+t]*(1.f/NN) - m*m;
    float s = rsqrtf(v+1e-5f);
    sc[t]=s; sh[t]=-m*s;
  }
  __syncthreads();
  int s0=starts[b], s1=starts[b+1];
  int f=t&127, half=t>>7;
  float acc=0.f;
  for (int n=s0+half;n<s1;n+=2){
    float v = h2raw[(size_t)n*128+f]*sc[f]+sh[f];
    acc += fmaxf(v,0.f);
  }
  red[t]=acc; __syncthreads();
  if (half==0){
    int cnt = s1-s0;
    g[b*128+f] = (red[f]+red[128+f]) / fmaxf((float)cnt, 1.f);
  }
}

// ---------------- FC head ----------------
__global__ __launch_bounds__(256) void k_head1(const float* __restrict__ g,
    const float* __restrict__ Wf1, const float* __restrict__ bf1, float* __restrict__ g1){
  __shared__ float sg[128];
  int r=blockIdx.x, t=threadIdx.x;
  if (t<128) sg[t]=g[r*128+t];
  __syncthreads();
  float acc=bf1[t];
  #pragma unroll 4
  for (int k=0;k<128;k++) acc += sg[k]*Wf1[k*256+t];
  g1[r*256+t]=acc;
}

__global__ __launch_bounds__(256) void k_head2(const float* __restrict__ g1,
    const float* __restrict__ stats, const float* __restrict__ Wf2,
    const float* __restrict__ bf2, float* __restrict__ g2){
  __shared__ float sin_[256];
  int r=blockIdx.x, t=threadIdx.x;
  float m = stats[t]*(1.f/NGB);
  float v = stats[256+t]*(1.f/NGB) - m*m;
  float val = (g1[r*256+t]-m)*rsqrtf(v+1e-5f);
  sin_[t]=fmaxf(val,0.f);
  __syncthreads();
  if (t<128){
    float acc=bf2[t];
    #pragma unroll 4
    for (int k=0;k<256;k++) acc += sin_[k]*Wf2[k*128+t];
    g2[r*128+t]=acc;
  }
}

__global__ __launch_bounds__(256) void k_head3(const float* __restrict__ g2,
    const float* __restrict__ stats, const float* __restrict__ Wf3,
    const float* __restrict__ bf3, float* __restrict__ out){
  __shared__ float sin_[128];
  int r=blockIdx.x, t=threadIdx.x;
  if (t<128){
    float m = stats[t]*(1.f/NGB);
    float v = stats[128+t]*(1.f/NGB) - m*m;
    float val = (g2[r*128+t]-m)*rsqrtf(v+1e-5f);
    sin_[t]=fmaxf(val,0.f);
  }
  __syncthreads();
  if (t<64){
    float acc=bf3[t];
    #pragma unroll 4
    for (int k=0;k<128;k++) acc += sin_[k]*Wf3[k*64+t];
    out[r*64+t]=acc;
  }
}

extern "C" void kernel_launch(void* const* d_in, const int* in_sizes, int n_in,
                              void* d_out, int out_size, void* d_ws, size_t ws_size,
                              hipStream_t stream){
  const float* x    = (const float*)d_in[0];
  const int*   ei   = (const int*)d_in[1];
  const float* ea   = (const float*)d_in[2];
  const int*   batch= (const int*)d_in[3];
  const float* We1=(const float*)d_in[4];  const float* be1=(const float*)d_in[5];
  const float* We2=(const float*)d_in[6];  const float* be2=(const float*)d_in[7];
  const float* We3=(const float*)d_in[8];  const float* be3=(const float*)d_in[9];
  const float* Wroot=(const float*)d_in[10]; const float* bc1=(const float*)d_in[11];
  const float* Wg1=(const float*)d_in[12]; const float* as1=(const float*)d_in[13];
  const float* ad1=(const float*)d_in[14]; const float* bg1=(const float*)d_in[15];
  const float* Wg2=(const float*)d_in[16]; const float* as2=(const float*)d_in[17];
  const float* ad2=(const float*)d_in[18]; const float* bg2=(const float*)d_in[19];
  const float* Wf1=(const float*)d_in[20]; const float* bf1=(const float*)d_in[21];
  const float* Wf2=(const float*)d_in[22]; const float* bf2=(const float*)d_in[23];
  const float* Wf3=(const float*)d_in[24]; const float* bf3=(const float*)d_in[25];
  (void)in_sizes; (void)n_in; (void)out_size; (void)ws_size;
  float* out = (float*)d_out;
  char* ws = (char*)d_ws;
  const int* srcA = ei;
  const int* dstA = ei + NE;

  size_t off = 0;
  auto take = [&](size_t bytes)->size_t{ size_t r = off; off += (bytes + 255) & ~(size_t)255; return r; };
  // zero region
  size_t o_deg_src = take(NN*4), o_deg_dst = take(NN*4);
  size_t o_fill_src = take(NN*4), o_fill_dst = take(NN*4);
  size_t o_stats0 = take(2*32*4), o_stats1 = take(2*64*4), o_stats2 = take(2*128*4);
  size_t o_statsH1 = take(2*256*4), o_statsH2 = take(2*128*4);
  size_t zero_bytes = off;
  // rest
  size_t o_rp_src = take((NN+1)*4), o_rp_dst = take((NN+1)*4);
  size_t o_pos_src = take((size_t)NE*4);
  size_t o_dstp = take((size_t)NE*4);
  size_t o_srcd = take((size_t)NE*4);
  size_t o_starts = take((NGB+1)*4);
  size_t o_W1p = take(4096*2);
  size_t o_W2p = take(8192*2);
  size_t o_t2p = take((size_t)(NE+8)*64*4);
  size_t o_Yp  = take((size_t)NN*1024*4);
  size_t o_xb  = take((size_t)NN*32*4);
  size_t o_agg = take((size_t)NN*32*4);
  size_t o_hW1b = take((size_t)NN*64*2);
  size_t o_scs1 = take(NN*4), o_scd1 = take(NN*4);
  size_t o_h1  = take((size_t)NN*64*4);
  size_t o_hW2b = take((size_t)NN*128*2);
  size_t o_scs2 = take(NN*4), o_scd2 = take(NN*4);
  size_t o_h2  = take((size_t)NN*128*4);
  size_t o_g   = take(NGB*128*4);
  size_t o_g1  = take(NGB*256*4);
  size_t o_g2  = take(NGB*128*4);

  #define WF(o) ((float*)(ws + (o)))
  #define WI(o) ((int*)(ws + (o)))
  #define WU(o) ((unsigned short*)(ws + (o)))
  #define WW(o) ((unsigned*)(ws + (o)))

  hipMemsetAsync(ws, 0, zero_bytes, stream);
  k_degrees<<<(NE+255)/256,256,0,stream>>>(srcA,dstA,WI(o_deg_src),WI(o_deg_dst));
  k_scan<<<2,1024,0,stream>>>(WI(o_deg_src),WI(o_deg_dst),WI(o_rp_src),WI(o_rp_dst));
  k_fill<<<(NE+255)/256,256,0,stream>>>(srcA,dstA,WI(o_rp_src),WI(o_rp_dst),
                                        WI(o_fill_src),WI(o_fill_dst),
                                        WI(o_pos_src),WI(o_dstp),WI(o_srcd));
  k_bounds<<<(NN+256)/256,256,0,stream>>>(batch,WI(o_starts));

  k_pack<<<1,256,0,stream>>>(We1,be1,We2,WU(o_W1p),WU(o_W2p));
  k_edge_mlp2<<<500,256,0,stream>>>(ea,WU(o_W1p),WU(o_W2p),be2,WI(o_pos_src),WF(o_t2p));
  k_y3<<<1024,256,0,stream>>>(x,We3,WW(o_Yp));
  k_xbagg<<<256,256,0,stream>>>(x,be3,Wroot,bc1,WF(o_xb),WF(o_agg));
  k_msg2<<<1250,256,0,stream>>>(WW(o_Yp),WF(o_xb),WF(o_t2p),WI(o_rp_src),WI(o_dstp),WF(o_agg));

  k_stats<<<64,256,0,stream>>>(WF(o_agg),NN,32,WF(o_stats0));
  k_gat_linear<32,64><<<640,256,0,stream>>>(WF(o_agg),WF(o_stats0),Wg1,as1,ad1,
                                            WU(o_hW1b),WF(o_scs1),WF(o_scd1));
  k_gat_attn2<64><<<640,256,0,stream>>>(WU(o_hW1b),WF(o_scs1),WF(o_scd1),
                                        WI(o_rp_dst),WI(o_srcd),bg1,WF(o_h1));
  k_stats<<<64,256,0,stream>>>(WF(o_h1),NN,64,WF(o_stats1));
  k_gat_linear<64,128><<<640,256,0,stream>>>(WF(o_h1),WF(o_stats1),Wg2,as2,ad2,
                                             WU(o_hW2b),WF(o_scs2),WF(o_scd2));
  k_gat_attn2<128><<<640,256,0,stream>>>(WU(o_hW2b),WF(o_scs2),WF(o_scd2),
                                         WI(o_rp_dst),WI(o_srcd),bg2,WF(o_h2));
  k_stats<<<64,256,0,stream>>>(WF(o_h2),NN,128,WF(o_stats2));

  k_pool<<<NGB,256,0,stream>>>(WF(o_h2),WF(o_stats2),WI(o_starts),WF(o_g));
  k_head1<<<NGB,256,0,stream>>>(WF(o_g),Wf1,bf1,WF(o_g1));
  k_stats<<<64,256,0,stream>>>(WF(o_g1),NGB,256,WF(o_statsH1));
  k_head2<<<NGB,256,0,stream>>>(WF(o_g1),WF(o_statsH1),Wf2,bf2,WF(o_g2));
  k_stats<<<64,256,0,stream>>>(WF(o_g2),NGB,128,WF(o_statsH2));
  k_head3<<<NGB,256,0,stream>>>(WF(o_g2),WF(o_statsH2),Wf3,bf3,out);
}

// Round 5
// 353.155 us; speedup vs baseline: 1.7629x; 1.0607x over previous
//
#include <hip/hip_runtime.h>

#define NN 10000      // nodes
#define NE 160000     // edges
#define NGB 100       // graphs

typedef __attribute__((ext_vector_type(8))) short s8v;   // 8 x bf16 (4 VGPR)
typedef __attribute__((ext_vector_type(4))) float f4v;   // MFMA accumulator

static __device__ __forceinline__ float lrelu(float v){ return v > 0.f ? v : 0.2f*v; }
static __device__ __forceinline__ unsigned short f2bf(float f){
  unsigned u = __float_as_uint(f);
  u += 0x7fffu + ((u >> 16) & 1u);
  return (unsigned short)(u >> 16);
}
static __device__ __forceinline__ float bf2f(unsigned short h){
  return __uint_as_float(((unsigned)h) << 16);
}
static __device__ __forceinline__ unsigned pack2(float a, float b){
  return (unsigned)f2bf(a) | ((unsigned)f2bf(b) << 16);
}

// ---------------- CSR build ----------------
__global__ __launch_bounds__(256) void k_degrees(const int* __restrict__ src, const int* __restrict__ dst,
                                                 int* deg_src, int* deg_dst){
  int i = blockIdx.x*256 + threadIdx.x;
  if (i < NE){ atomicAdd(&deg_src[src[i]],1); atomicAdd(&deg_dst[dst[i]],1); }
}

__global__ __launch_bounds__(1024) void k_scan(const int* __restrict__ deg_src, const int* __restrict__ deg_dst,
                                               int* rp_src, int* rp_dst){
  const int* deg = (blockIdx.x==0) ? deg_src : deg_dst;
  int* rp = (blockIdx.x==0) ? rp_src : rp_dst;
  __shared__ int part[1024];
  int tid = threadIdx.x;
  const int per = (NN + 1023)/1024;   // 10
  int base = tid*per;
  int s = 0;
  for (int i=0;i<per;i++){ int idx=base+i; if (idx<NN) s += deg[idx]; }
  part[tid]=s; __syncthreads();
  for (int off=1; off<1024; off<<=1){
    int v = part[tid];
    int add = (tid>=off) ? part[tid-off] : 0;
    __syncthreads();
    part[tid] = v + add;
    __syncthreads();
  }
  int run = (tid==0) ? 0 : part[tid-1];
  for (int i=0;i<per;i++){ int idx=base+i; if (idx<NN){ rp[idx]=run; run += deg[idx]; } }
  if (tid==1023) rp[NN] = part[1023];
}

// pos_src[e]: slot of edge e in CSR-src order; dstp[p]=dst of edge at src-slot p;
// srcd[q]=src of edge at dst-slot q.
__global__ __launch_bounds__(256) void k_fill(const int* __restrict__ src, const int* __restrict__ dst,
                       const int* __restrict__ rp_src, const int* __restrict__ rp_dst,
                       int* fill_src, int* fill_dst, int* pos_src, int* dstp, int* srcd){
  int i = blockIdx.x*256 + threadIdx.x;
  if (i < NE){
    int s=src[i], d=dst[i];
    int p=rp_src[s]+atomicAdd(&fill_src[s],1); pos_src[i]=p; dstp[p]=d;
    int q=rp_dst[d]+atomicAdd(&fill_dst[d],1); srcd[q]=s;
  }
}

__global__ __launch_bounds__(256) void k_bounds(const int* __restrict__ batch, int* starts){
  int n = blockIdx.x*256 + threadIdx.x;
  if (n > NN) return;
  int cur  = (n==NN) ? NGB : batch[n];
  int prev = (n==0)  ? -1  : batch[n-1];
  for (int b=prev+1; b<=cur; b++) if (b<=NGB) starts[b]=n;
}

// ---------------- weight pack for MFMA edge MLP ----------------
__global__ __launch_bounds__(256) void k_pack(const float* __restrict__ We1, const float* __restrict__ be1,
    const float* __restrict__ We2, unsigned short* __restrict__ W1p, unsigned short* __restrict__ W2p){
  int tid = threadIdx.x;
  for (int idx=tid; idx<512; idx+=256){
    int j=idx>>6, l=idx&63, col=l&15, g=l>>4;
    int out = j*16+col;
    #pragma unroll
    for (int jj=0;jj<8;jj++){
      int k = g*8+jj;
      float v = (k<16) ? We1[k*128+out] : (k==16 ? be1[out] : 0.f);
      W1p[idx*8+jj] = f2bf(v);
    }
  }
  for (int idx=tid; idx<1024; idx+=256){
    int ft=idx>>6, l=idx&63, col=l&15, g=l>>4;
    int t=ft>>2, jo=ft&3;
    int out = jo*16+col;
    #pragma unroll
    for (int jj=0;jj<8;jj++){
      int k = t*32+g*8+jj;
      W2p[idx*8+jj] = f2bf(We2[k*64+out]);
    }
  }
}

// ---------------- W3 pack (A-fragments, hi/lo split) for k_y4 ----------------
// W'[f][j] = We3[j>>5, f*32 + (j&31)]; A-frag tile jt: lane l -> row j=jt*16+(l&15), f=(l>>4)*8+jj
__global__ __launch_bounds__(256) void k_pack3(const float* __restrict__ We3,
    unsigned short* __restrict__ W3h, unsigned short* __restrict__ W3l){
  int idx = blockIdx.x*256 + threadIdx.x;   // [0, 8192)
  if (idx >= 128*64) return;
  int jt = idx>>6, l = idx&63;
  int j = jt*16 + (l&15);
  int f0 = (l>>4)*8;
  int k = j>>5, o = j&31;
  #pragma unroll
  for (int jj=0;jj<8;jj++){
    float v = We3[(size_t)k*1024 + (size_t)(f0+jj)*32 + o];
    unsigned short h = f2bf(v);
    float r = v - bf2f(h);
    W3h[(size_t)idx*8+jj] = h;
    W3l[(size_t)idx*8+jj] = f2bf(r);
  }
}

// ---------------- EdgeMLP via MFMA -> t2 rows scattered into CSR-src order ----------------
__global__ __launch_bounds__(256) void k_edge_mlp2(const float* __restrict__ ea,
    const unsigned short* __restrict__ W1p, const unsigned short* __restrict__ W2p,
    const float* __restrict__ be2, const int* __restrict__ pos_src, float* __restrict__ t2p){
  __shared__ unsigned short st1[4*2048];   // [wave][16 edges][128 k] bf16, XOR-swizzled
  int tid=threadIdx.x, wave=tid>>6, lane=tid&63;
  int c = lane&15, g = lane>>4;
  s8v w1f[8], w2f[16];
  #pragma unroll
  for (int j=0;j<8;j++)  w1f[j] = *(const s8v*)(W1p + (size_t)(j*64+lane)*8);
  #pragma unroll
  for (int q=0;q<16;q++) w2f[q] = *(const s8v*)(W2p + (size_t)(q*64+lane)*8);
  float be2v[16];
  #pragma unroll
  for (int jo=0;jo<4;jo++)
    #pragma unroll
    for (int r=0;r<4;r++) be2v[jo*4+r] = be2[jo*16+g*4+r];
  char* myld = (char*)(st1 + wave*2048);
  const f4v fzero = {0.f,0.f,0.f,0.f};

  for (int base = blockIdx.x*64; base < NE; base += gridDim.x*64){
    int e0 = base + wave*16;
    s8v eaf = {0,0,0,0,0,0,0,0};
    if (g < 2){
      const float* p = ea + (size_t)(e0+c)*16 + g*8;
      float4 a = *(const float4*)p;
      float4 b = *(const float4*)(p+4);
      eaf[0]=(short)f2bf(a.x); eaf[1]=(short)f2bf(a.y); eaf[2]=(short)f2bf(a.z); eaf[3]=(short)f2bf(a.w);
      eaf[4]=(short)f2bf(b.x); eaf[5]=(short)f2bf(b.y); eaf[6]=(short)f2bf(b.z); eaf[7]=(short)f2bf(b.w);
    } else if (g == 2){
      eaf[0] = (short)0x3f80;  // bf16(1.0) bias slot
    }
    f4v acc1[8];
    #pragma unroll
    for (int j=0;j<8;j++)
      acc1[j] = __builtin_amdgcn_mfma_f32_16x16x32_bf16(w1f[j], eaf, fzero, 0, 0, 0);
    #pragma unroll
    for (int j=0;j<8;j++){
      unsigned lo = pack2(fmaxf(acc1[j][0],0.f), fmaxf(acc1[j][1],0.f));
      unsigned hi = pack2(fmaxf(acc1[j][2],0.f), fmaxf(acc1[j][3],0.f));
      unsigned off = (unsigned)(c*256 + ((j*32 + g*8) ^ (c<<4)));
      *(uint2*)(myld + off) = make_uint2(lo, hi);
    }
    __syncthreads();
    f4v acc2[4];
    #pragma unroll
    for (int jo=0;jo<4;jo++) acc2[jo] = fzero;
    #pragma unroll
    for (int t=0;t<4;t++){
      unsigned off = (unsigned)(c*256 + ((t*64 + g*16) ^ (c<<4)));
      s8v b2 = *(const s8v*)(myld + off);
      #pragma unroll
      for (int jo=0;jo<4;jo++)
        acc2[jo] = __builtin_amdgcn_mfma_f32_16x16x32_bf16(w2f[t*4+jo], b2, acc2[jo], 0, 0, 0);
    }
    int pos = pos_src[e0+c];
    float* orow = t2p + (size_t)pos*64;
    #pragma unroll
    for (int jo=0;jo<4;jo++){
      f4v v;
      #pragma unroll
      for (int r=0;r<4;r++) v[r] = fmaxf(acc2[jo][r] + be2v[jo*4+r], 0.f);
      *(f4v*)(orow + jo*16 + g*4) = v;
    }
    __syncthreads();
  }
}

// ---------------- Y via MFMA (hi/lo split, fp32-grade): Yp bf16-pair swizzled rows ----------------
// wave: one 16-node tile x 64 jt tiles. D[j-row][n-col]. LDS-stage transpose for coalesced dwordx4 stores.
__global__ __launch_bounds__(256) void k_y4(const float* __restrict__ x,
    const unsigned short* __restrict__ W3h, const unsigned short* __restrict__ W3l,
    unsigned* __restrict__ Yp){
  __shared__ __align__(16) unsigned stage[4][16][128];  // [wave][node][loc ^ (c<<2)]
  int tid=threadIdx.x, w=tid>>6, l=tid&63;
  int c = l&15, g = l>>4;
  int tile = blockIdx.x*2 + (w>>1);
  if (tile >= 625) return;
  int jt0 = (w&1)*64;
  int n = tile*16 + c;
  const float* xr = x + (size_t)n*32 + g*8;
  float4 xa = *(const float4*)xr;
  float4 xc = *(const float4*)(xr+4);
  float xv[8] = {xa.x,xa.y,xa.z,xa.w,xc.x,xc.y,xc.z,xc.w};
  s8v bh, bl;
  #pragma unroll
  for (int jj=0;jj<8;jj++){
    unsigned short h = f2bf(xv[jj]);
    bh[jj] = (short)h;
    bl[jj] = (short)f2bf(xv[jj] - bf2f(h));
  }
  const f4v fz = {0.f,0.f,0.f,0.f};
  for (int grp=0; grp<4; grp++){           // 16 jt per group
    #pragma unroll 4
    for (int jtl=0; jtl<16; jtl++){
      int jt = jt0 + grp*16 + jtl;
      s8v Ah = *(const s8v*)(W3h + (size_t)(jt*64 + l)*8);
      s8v Al = *(const s8v*)(W3l + (size_t)(jt*64 + l)*8);
      f4v acc = __builtin_amdgcn_mfma_f32_16x16x32_bf16(Ah, bl, fz, 0, 0, 0);
      acc = __builtin_amdgcn_mfma_f32_16x16x32_bf16(Al, bh, acc, 0, 0, 0);
      acc = __builtin_amdgcn_mfma_f32_16x16x32_bf16(Ah, bh, acc, 0, 0, 0);
      int j0 = jt*16 + g*4;
      int oh0 = (j0 & 31) >> 1;            // even
      int k = j0 >> 5;
      int kcl = (k>>2)&1, r = k&3;
      unsigned loc0 = ((unsigned)oh0<<3) | ((unsigned)kcl<<2) | (unsigned)r;
      stage[w][c][loc0 ^ (unsigned)(c<<2)]       = pack2(acc[0], acc[1]);
      stage[w][c][(loc0+8u) ^ (unsigned)(c<<2)]  = pack2(acc[2], acc[3]);
    }
    __builtin_amdgcn_wave_barrier();
    int kbase = (jt0 + grp*16) >> 1;       // first k of group (mult of 8)
    int kc0 = kbase >> 2;                   // even
    #pragma unroll
    for (int ps=0; ps<8; ps++){
      int comb = ps*4 + g;                 // oh = comb>>1, kcl = comb&1
      int oh = comb>>1, kcl = comb&1;
      unsigned loc = ((((unsigned)oh<<3) | ((unsigned)kcl<<2)) ^ (unsigned)(c<<2));
      uint4 v = *(const uint4*)(&stage[w][c][loc]);
      int kc = kc0 + kcl;
      unsigned gidx = ((unsigned)oh<<6) | (unsigned)(((kc ^ oh)&15)<<2);
      *(uint4*)(Yp + (size_t)n*1024 + gidx) = v;
    }
    __builtin_amdgcn_wave_barrier();
  }
}

// ---------------- xb[n,o] = x@be3-fold ; agg-init = x@Wroot + bc1 ----------------
__global__ __launch_bounds__(256) void k_xbagg(const float* __restrict__ x,
    const float* __restrict__ be3, const float* __restrict__ Wroot, const float* __restrict__ bc1,
    float* __restrict__ xb, float* __restrict__ agg){
  __shared__ __align__(16) float sx[8][32];
  int oo = threadIdx.x & 31, nn = threadIdx.x >> 5;
  float wb[32], wr[32];
  #pragma unroll
  for (int f=0;f<32;f++){ wb[f]=be3[f*32+oo]; wr[f]=Wroot[f*32+oo]; }
  float bcv = bc1[oo];
  int per = (1250 + gridDim.x - 1)/gridDim.x;
  int g0 = blockIdx.x*per, g1 = min(g0+per, 1250);
  for (int gi=g0; gi<g1; gi++){
    int nb = gi*8;
    __syncthreads();
    sx[threadIdx.x>>5][threadIdx.x&31] = x[(size_t)nb*32 + threadIdx.x];
    __syncthreads();
    float a1=0.f, a2=0.f;
    #pragma unroll
    for (int f4=0;f4<8;f4++){
      float4 xv = *(const float4*)(&sx[nn][f4*4]);
      a1 += xv.x*wb[f4*4+0]+xv.y*wb[f4*4+1]+xv.z*wb[f4*4+2]+xv.w*wb[f4*4+3];
      a2 += xv.x*wr[f4*4+0]+xv.y*wr[f4*4+1]+xv.z*wr[f4*4+2]+xv.w*wr[f4*4+3];
    }
    xb[(size_t)(nb+nn)*32+oo] = a1;
    agg[(size_t)(nb+nn)*32+oo] = a2 + bcv;
  }
}

// ---------------- msg+aggregate fused: agg[dst] += xb[src] + t2[e]·Yrow(src) ----------------
__global__ __launch_bounds__(256) void k_msg2(const unsigned* __restrict__ Yp,
    const float* __restrict__ xb, const float* __restrict__ t2p,
    const int* __restrict__ rp_src, const int* __restrict__ dstp,
    float* __restrict__ agg){
  __shared__ __align__(16) unsigned sY[4][1024];
  __shared__ __align__(16) float sT[4][256];
  int tid=threadIdx.x, w=tid>>6, lane=tid&63;
  int es = lane>>4, l = lane&15;
  int gw = blockIdx.x*4 + w, stride = gridDim.x*4;
  for (int n=gw; n<NN; n+=stride){
    int beg=rp_src[n], end=rp_src[n+1];
    if (beg==end) continue;
    const unsigned* Yr = Yp + (size_t)n*1024;
    #pragma unroll
    for (int q=0;q<4;q++){
      uint4 v = *(const uint4*)(Yr + q*256 + lane*4);
      *(uint4*)(&sY[w][q*256 + lane*4]) = v;
    }
    float2 xbv = *(const float2*)(xb + (size_t)n*32 + 2*l);
    __builtin_amdgcn_wave_barrier();
    for (int pb=beg; pb<end; pb+=4){
      {
        float4 tv = *(const float4*)(t2p + (size_t)pb*64 + lane*4);
        int te = lane>>4, tk = lane&15;
        *(float4*)(&sT[w][(te*16 + (tk^te))*4]) = tv;
      }
      __builtin_amdgcn_wave_barrier();
      float acc0 = xbv.x, acc1 = xbv.y;
      #pragma unroll
      for (int kc=0;kc<16;kc++){
        float4 t = *(const float4*)(&sT[w][(es*16 + (kc^es))*4]);
        uint4 y = *(const uint4*)(&sY[w][(l*16 + (kc^l))*4]);
        acc0 += t.x*__uint_as_float(y.x<<16);
        acc1 += t.x*__uint_as_float(y.x&0xffff0000u);
        acc0 += t.y*__uint_as_float(y.y<<16);
        acc1 += t.y*__uint_as_float(y.y&0xffff0000u);
        acc0 += t.z*__uint_as_float(y.z<<16);
        acc1 += t.z*__uint_as_float(y.z&0xffff0000u);
        acc0 += t.w*__uint_as_float(y.w<<16);
        acc1 += t.w*__uint_as_float(y.w&0xffff0000u);
      }
      int p = pb + es;
      if (p < end){
        int d = dstp[p];
        float* ap = agg + (size_t)d*32 + 2*l;
        unsafeAtomicAdd(ap,   acc0);
        unsafeAtomicAdd(ap+1, acc1);
      }
      __builtin_amdgcn_wave_barrier();
    }
  }
}

// ---------------- column stats (sum, sumsq) for BN; stats pre-zeroed ----------------
__global__ __launch_bounds__(256) void k_stats(const float* __restrict__ buf, int nrows, int ncols,
                                               float* __restrict__ stats){
  int tid = threadIdx.x;
  int c  = tid % ncols;
  int r0 = tid / ncols;
  int rp = 256 / ncols;
  float s1=0.f, s2=0.f;
  for (long long base=(long long)blockIdx.x*rp; base<nrows; base+=(long long)gridDim.x*rp){
    int r = (int)base + r0;
    if (r < nrows){
      float v = buf[(size_t)r*ncols + c];
      s1 += v; s2 += v*v;
    }
  }
  __shared__ float A[256], B[256];
  A[tid]=s1; B[tid]=s2; __syncthreads();
  if (tid < ncols){
    float t1=0.f, t2=0.f;
    for (int gg=0; gg<256/ncols; gg++){ t1 += A[gg*ncols+tid]; t2 += B[gg*ncols+tid]; }
    atomicAdd(&stats[tid], t1);
    atomicAdd(&stats[ncols+tid], t2);
  }
}

// ---------------- GAT linear: in=relu(bn(raw)); hWb=bf16(in@W); sc_s,sc_d ----------------
template<int FIN, int FOUT>
__global__ __launch_bounds__(256) void k_gat_linear(const float* __restrict__ raw,
    const float* __restrict__ stats, const float* __restrict__ W,
    const float* __restrict__ avs, const float* __restrict__ avd,
    unsigned short* __restrict__ hWb, float* __restrict__ sc_s, float* __restrict__ sc_d){
  __shared__ float sW[FIN*FOUT];
  __shared__ float sA[FOUT], sD[FOUT];
  __shared__ float sScale[FIN], sShift[FIN];
  __shared__ float sIn[4][FIN];
  int tid = threadIdx.x;
  for (int i=tid;i<FIN*FOUT;i+=256) sW[i]=W[i];
  if (tid<FOUT){ sA[tid]=avs[tid]; sD[tid]=avd[tid]; }
  if (tid<FIN){
    float m = stats[tid]*(1.f/NN);
    float v = stats[FIN+tid]*(1.f/NN) - m*m;
    float s = rsqrtf(v + 1e-5f);
    sScale[tid]=s; sShift[tid]=-m*s;
  }
  __syncthreads();
  int wave=tid>>6, lane=tid&63;
  for (int nb = blockIdx.x*4; nb < NN; nb += gridDim.x*4){
    int n = nb + wave;
    bool act = n < NN;
    if (act){
      for (int ff=lane; ff<FIN; ff+=64){
        float vv = raw[(size_t)n*FIN+ff]*sScale[ff]+sShift[ff];
        sIn[wave][ff] = fmaxf(vv, 0.f);
      }
    }
    __syncthreads();
    if (act){
      float out0=0.f, out1=0.f;
      #pragma unroll
      for (int ff=0; ff<FIN; ff++){
        float xv = sIn[wave][ff];
        out0 += xv*sW[ff*FOUT+lane];
        if constexpr (FOUT > 64) out1 += xv*sW[ff*FOUT+lane+64];
      }
      hWb[(size_t)n*FOUT + lane] = f2bf(out0);
      float ps = out0*sA[lane], pd = out0*sD[lane];
      if constexpr (FOUT > 64){
        hWb[(size_t)n*FOUT + lane + 64] = f2bf(out1);
        ps += out1*sA[lane+64]; pd += out1*sD[lane+64];
      }
      #pragma unroll
      for (int off=32;off>0;off>>=1){ ps += __shfl_down(ps,off); pd += __shfl_down(pd,off); }
      if (lane==0){ sc_s[n]=ps; sc_d[n]=pd; }
    }
    __syncthreads();
  }
}

// ---------------- GAT attention: single pass, online softmax, bf16 gathers ----------------
template<int F>
__global__ __launch_bounds__(256) void k_gat_attn2(const unsigned short* __restrict__ hWb,
    const float* __restrict__ sc_s, const float* __restrict__ sc_d,
    const int* __restrict__ rp_dst, const int* __restrict__ srcd,
    const float* __restrict__ bias, float* __restrict__ outraw){
  __shared__ float sp[4][64];
  __shared__ int ssi[4][64];
  int tid=threadIdx.x, w=tid>>6, lane=tid&63;
  int gw = blockIdx.x*4 + w, stride = gridDim.x*4;
  for (int n=gw; n<NN; n+=stride){
    int beg=rp_dst[n], end=rp_dst[n+1];
    float scd = sc_d[n];
    float M=-3e38f, S=0.f, acc0=0.f, acc1=0.f;
    for (int base=beg; base<end; base+=64){
      int nb = min(64, end-base);
      int si=0; float sc=-3e38f;
      if (lane<nb){ si = srcd[base+lane]; sc = lrelu(sc_s[si]+scd); }
      float cm=sc;
      #pragma unroll
      for (int off=32;off>0;off>>=1) cm = fmaxf(cm, __shfl_xor(cm,off));
      float Mn = fmaxf(M, cm);
      float p = (lane<nb) ? __expf(sc-Mn) : 0.f;
      float ps=p;
      #pragma unroll
      for (int off=32;off>0;off>>=1) ps += __shfl_xor(ps,off);
      float scale = __expf(M-Mn);
      S = S*scale + ps;
      acc0*=scale; acc1*=scale;
      sp[w][lane]=p; ssi[w][lane]=si;
      __builtin_amdgcn_wave_barrier();
      for (int jj=0;jj<nb;jj++){
        float pj = sp[w][jj]; int sj = ssi[w][jj];
        if constexpr (F==128){
          unsigned u = *(const unsigned*)(hWb + (size_t)sj*128 + 2*lane);
          acc0 += pj*__uint_as_float(u<<16);
          acc1 += pj*__uint_as_float(u&0xffff0000u);
        } else {
          acc0 += pj*__uint_as_float(((unsigned)hWb[(size_t)sj*64+lane])<<16);
        }
      }
      __builtin_amdgcn_wave_barrier();
      M = Mn;
    }
    float sself = lrelu(sc_s[n]+scd);
    float Mn = fmaxf(M, sself);
    float scale = __expf(M-Mn);
    float pself = __expf(sself-Mn);
    S = S*scale + pself;
    acc0*=scale; acc1*=scale;
    float inv;
    if constexpr (F==128){
      unsigned u = *(const unsigned*)(hWb + (size_t)n*128 + 2*lane);
      acc0 += pself*__uint_as_float(u<<16);
      acc1 += pself*__uint_as_float(u&0xffff0000u);
      inv = 1.f/(S+1e-16f);
      float2 ov;
      ov.x = acc0*inv + bias[2*lane];
      ov.y = acc1*inv + bias[2*lane+1];
      *(float2*)(outraw + (size_t)n*128 + 2*lane) = ov;
    } else {
      acc0 += pself*__uint_as_float(((unsigned)hWb[(size_t)n*64+lane])<<16);
      inv = 1.f/(S+1e-16f);
      outraw[(size_t)n*64+lane] = acc0*inv + bias[lane];
    }
  }
}

// ---------------- mean pool with bn+relu on read ----------------
__global__ __launch_bounds__(256) void k_pool(const float* __restrict__ h2raw,
    const float* __restrict__ stats, const int* __restrict__ starts,
    float* __restrict__ g){
  __shared__ float sc[128], sh[128];
  __shared__ float red[256];
  int b=blockIdx.x, t=threadIdx.x;
  if (t<128){
    float m = stats[t]*(1.f/NN);
    float v = stats[128+t]*(1.f/NN) - m*m;
    float s = rsqrtf(v+1e-5f);
    sc[t]=s; sh[t]=-m*s;
  }
  __syncthreads();
  int s0=starts[b], s1=starts[b+1];
  int f=t&127, half=t>>7;
  float acc=0.f;
  for (int n=s0+half;n<s1;n+=2){
    float v = h2raw[(size_t)n*128+f]*sc[f]+sh[f];
    acc += fmaxf(v,0.f);
  }
  red[t]=acc; __syncthreads();
  if (half==0){
    int cnt = s1-s0;
    g[b*128+f] = (red[f]+red[128+f]) / fmaxf((float)cnt, 1.f);
  }
}

// ---------------- FC head ----------------
__global__ __launch_bounds__(256) void k_head1(const float* __restrict__ g,
    const float* __restrict__ Wf1, const float* __restrict__ bf1, float* __restrict__ g1){
  __shared__ float sg[128];
  int r=blockIdx.x, t=threadIdx.x;
  if (t<128) sg[t]=g[r*128+t];
  __syncthreads();
  float acc=bf1[t];
  #pragma unroll 4
  for (int k=0;k<128;k++) acc += sg[k]*Wf1[k*256+t];
  g1[r*256+t]=acc;
}

__global__ __launch_bounds__(256) void k_head2(const float* __restrict__ g1,
    const float* __restrict__ stats, const float* __restrict__ Wf2,
    const float* __restrict__ bf2, float* __restrict__ g2){
  __shared__ float sin_[256];
  int r=blockIdx.x, t=threadIdx.x;
  float m = stats[t]*(1.f/NGB);
  float v = stats[256+t]*(1.f/NGB) - m*m;
  float val = (g1[r*256+t]-m)*rsqrtf(v+1e-5f);
  sin_[t]=fmaxf(val,0.f);
  __syncthreads();
  if (t<128){
    float acc=bf2[t];
    #pragma unroll 4
    for (int k=0;k<256;k++) acc += sin_[k]*Wf2[k*128+t];
    g2[r*128+t]=acc;
  }
}

__global__ __launch_bounds__(256) void k_head3(const float* __restrict__ g2,
    const float* __restrict__ stats, const float* __restrict__ Wf3,
    const float* __restrict__ bf3, float* __restrict__ out){
  __shared__ float sin_[128];
  int r=blockIdx.x, t=threadIdx.x;
  if (t<128){
    float m = stats[t]*(1.f/NGB);
    float v = stats[128+t]*(1.f/NGB) - m*m;
    float val = (g2[r*128+t]-m)*rsqrtf(v+1e-5f);
    sin_[t]=fmaxf(val,0.f);
  }
  __syncthreads();
  if (t<64){
    float acc=bf3[t];
    #pragma unroll 4
    for (int k=0;k<128;k++) acc += sin_[k]*Wf3[k*64+t];
    out[r*64+t]=acc;
  }
}

extern "C" void kernel_launch(void* const* d_in, const int* in_sizes, int n_in,
                              void* d_out, int out_size, void* d_ws, size_t ws_size,
                              hipStream_t stream){
  const float* x    = (const float*)d_in[0];
  const int*   ei   = (const int*)d_in[1];
  const float* ea   = (const float*)d_in[2];
  const int*   batch= (const int*)d_in[3];
  const float* We1=(const float*)d_in[4];  const float* be1=(const float*)d_in[5];
  const float* We2=(const float*)d_in[6];  const float* be2=(const float*)d_in[7];
  const float* We3=(const float*)d_in[8];  const float* be3=(const float*)d_in[9];
  const float* Wroot=(const float*)d_in[10]; const float* bc1=(const float*)d_in[11];
  const float* Wg1=(const float*)d_in[12]; const float* as1=(const float*)d_in[13];
  const float* ad1=(const float*)d_in[14]; const float* bg1=(const float*)d_in[15];
  const float* Wg2=(const float*)d_in[16]; const float* as2=(const float*)d_in[17];
  const float* ad2=(const float*)d_in[18]; const float* bg2=(const float*)d_in[19];
  const float* Wf1=(const float*)d_in[20]; const float* bf1=(const float*)d_in[21];
  const float* Wf2=(const float*)d_in[22]; const float* bf2=(const float*)d_in[23];
  const float* Wf3=(const float*)d_in[24]; const float* bf3=(const float*)d_in[25];
  (void)in_sizes; (void)n_in; (void)out_size; (void)ws_size;
  float* out = (float*)d_out;
  char* ws = (char*)d_ws;
  const int* srcA = ei;
  const int* dstA = ei + NE;

  size_t off = 0;
  auto take = [&](size_t bytes)->size_t{ size_t r = off; off += (bytes + 255) & ~(size_t)255; return r; };
  // zero region
  size_t o_deg_src = take(NN*4), o_deg_dst = take(NN*4);
  size_t o_fill_src = take(NN*4), o_fill_dst = take(NN*4);
  size_t o_stats0 = take(2*32*4), o_stats1 = take(2*64*4), o_stats2 = take(2*128*4);
  size_t o_statsH1 = take(2*256*4), o_statsH2 = take(2*128*4);
  size_t zero_bytes = off;
  // rest
  size_t o_rp_src = take((NN+1)*4), o_rp_dst = take((NN+1)*4);
  size_t o_pos_src = take((size_t)NE*4);
  size_t o_dstp = take((size_t)NE*4);
  size_t o_srcd = take((size_t)NE*4);
  size_t o_starts = take((NGB+1)*4);
  size_t o_W1p = take(4096*2);
  size_t o_W2p = take(8192*2);
  size_t o_W3h = take((size_t)128*64*8*2);
  size_t o_W3l = take((size_t)128*64*8*2);
  size_t o_t2p = take((size_t)(NE+8)*64*4);
  size_t o_Yp  = take((size_t)NN*1024*4);
  size_t o_xb  = take((size_t)NN*32*4);
  size_t o_agg = take((size_t)NN*32*4);
  size_t o_hW1b = take((size_t)NN*64*2);
  size_t o_scs1 = take(NN*4), o_scd1 = take(NN*4);
  size_t o_h1  = take((size_t)NN*64*4);
  size_t o_hW2b = take((size_t)NN*128*2);
  size_t o_scs2 = take(NN*4), o_scd2 = take(NN*4);
  size_t o_h2  = take((size_t)NN*128*4);
  size_t o_g   = take(NGB*128*4);
  size_t o_g1  = take(NGB*256*4);
  size_t o_g2  = take(NGB*128*4);

  #define WF(o) ((float*)(ws + (o)))
  #define WI(o) ((int*)(ws + (o)))
  #define WU(o) ((unsigned short*)(ws + (o)))
  #define WW(o) ((unsigned*)(ws + (o)))

  hipMemsetAsync(ws, 0, zero_bytes, stream);
  k_degrees<<<(NE+255)/256,256,0,stream>>>(srcA,dstA,WI(o_deg_src),WI(o_deg_dst));
  k_scan<<<2,1024,0,stream>>>(WI(o_deg_src),WI(o_deg_dst),WI(o_rp_src),WI(o_rp_dst));
  k_fill<<<(NE+255)/256,256,0,stream>>>(srcA,dstA,WI(o_rp_src),WI(o_rp_dst),
                                        WI(o_fill_src),WI(o_fill_dst),
                                        WI(o_pos_src),WI(o_dstp),WI(o_srcd));
  k_bounds<<<(NN+256)/256,256,0,stream>>>(batch,WI(o_starts));

  k_pack<<<1,256,0,stream>>>(We1,be1,We2,WU(o_W1p),WU(o_W2p));
  k_pack3<<<32,256,0,stream>>>(We3,WU(o_W3h),WU(o_W3l));
  k_edge_mlp2<<<500,256,0,stream>>>(ea,WU(o_W1p),WU(o_W2p),be2,WI(o_pos_src),WF(o_t2p));
  k_y4<<<313,256,0,stream>>>(x,WU(o_W3h),WU(o_W3l),WW(o_Yp));
  k_xbagg<<<256,256,0,stream>>>(x,be3,Wroot,bc1,WF(o_xb),WF(o_agg));
  k_msg2<<<1250,256,0,stream>>>(WW(o_Yp),WF(o_xb),WF(o_t2p),WI(o_rp_src),WI(o_dstp),WF(o_agg));

  k_stats<<<64,256,0,stream>>>(WF(o_agg),NN,32,WF(o_stats0));
  k_gat_linear<32,64><<<640,256,0,stream>>>(WF(o_agg),WF(o_stats0),Wg1,as1,ad1,
                                            WU(o_hW1b),WF(o_scs1),WF(o_scd1));
  k_gat_attn2<64><<<640,256,0,stream>>>(WU(o_hW1b),WF(o_scs1),WF(o_scd1),
                                        WI(o_rp_dst),WI(o_srcd),bg1,WF(o_h1));
  k_stats<<<64,256,0,stream>>>(WF(o_h1),NN,64,WF(o_stats1));
  k_gat_linear<64,128><<<640,256,0,stream>>>(WF(o_h1),WF(o_stats1),Wg2,as2,ad2,
                                             WU(o_hW2b),WF(o_scs2),WF(o_scd2));
  k_gat_attn2<128><<<640,256,0,stream>>>(WU(o_hW2b),WF(o_scs2),WF(o_scd2),
                                         WI(o_rp_dst),WI(o_srcd),bg2,WF(o_h2));
  k_stats<<<64,256,0,stream>>>(WF(o_h2),NN,128,WF(o_stats2));

  k_pool<<<NGB,256,0,stream>>>(WF(o_h2),WF(o_stats2),WI(o_starts),WF(o_g));
  k_head1<<<NGB,256,0,stream>>>(WF(o_g),Wf1,bf1,WF(o_g1));
  k_stats<<<64,256,0,stream>>>(WF(o_g1),NGB,256,WF(o_statsH1));
  k_head2<<<NGB,256,0,stream>>>(WF(o_g1),WF(o_statsH1),Wf2,bf2,WF(o_g2));
  k_stats<<<64,256,0,stream>>>(WF(o_g2),NGB,128,WF(o_statsH2));
  k_head3<<<NGB,256,0,stream>>>(WF(o_g2),WF(o_statsH2),Wf3,bf3,out);
}

// Round 7
// 351.138 us; speedup vs baseline: 1.7730x; 1.0057x over previous
//
#include <hip/hip_runtime.h>

#define NN 10000      // nodes
#define NE 160000     // edges
#define NGB 100       // graphs

typedef __attribute__((ext_vector_type(8))) short s8v;     // 8 x bf16
typedef __attribute__((ext_vector_type(4))) float f4v;     // MFMA accumulator
typedef __attribute__((ext_vector_type(2))) _Float16 h2v;  // half2

static __device__ __forceinline__ float lrelu(float v){ return v > 0.f ? v : 0.2f*v; }
static __device__ __forceinline__ unsigned short f2bf(float f){
  unsigned u = __float_as_uint(f);
  u += 0x7fffu + ((u >> 16) & 1u);
  return (unsigned short)(u >> 16);
}
static __device__ __forceinline__ float bf2f(unsigned short h){
  return __uint_as_float(((unsigned)h) << 16);
}
static __device__ __forceinline__ unsigned pkh(float a, float b){
  auto h = __builtin_amdgcn_cvt_pkrtz(a, b);
  return __builtin_bit_cast(unsigned, h);
}
static __device__ __forceinline__ unsigned short f2h(float f){
  _Float16 h = (_Float16)f;
  return __builtin_bit_cast(unsigned short, h);
}
static __device__ __forceinline__ float h2f(unsigned short u){
  return (float)__builtin_bit_cast(_Float16, u);
}
static __device__ __forceinline__ float dot2h(unsigned t, unsigned y, float acc){
#if __has_builtin(__builtin_amdgcn_fdot2)
  return __builtin_amdgcn_fdot2(__builtin_bit_cast(h2v, t), __builtin_bit_cast(h2v, y), acc, false);
#else
  h2v a = __builtin_bit_cast(h2v, t), b = __builtin_bit_cast(h2v, y);
  return acc + (float)a[0]*(float)b[0] + (float)a[1]*(float)b[1];
#endif
}

// ---------------- CSR build (+ graph bounds fused) ----------------
__global__ __launch_bounds__(256) void k_deg_bounds(const int* __restrict__ src, const int* __restrict__ dst,
                                                    const int* __restrict__ batch,
                                                    int* deg_src, int* deg_dst, int* starts){
  int i = blockIdx.x*256 + threadIdx.x;
  if (i < NE){ atomicAdd(&deg_src[src[i]],1); atomicAdd(&deg_dst[dst[i]],1); }
  if (i <= NN){
    int cur  = (i==NN) ? NGB : batch[i];
    int prev = (i==0)  ? -1  : batch[i-1];
    for (int b=prev+1; b<=cur; b++) if (b<=NGB) starts[b]=i;
  }
}

__global__ __launch_bounds__(1024) void k_scan(const int* __restrict__ deg_src, const int* __restrict__ deg_dst,
                                               int* rp_src, int* rp_dst){
  const int* deg = (blockIdx.x==0) ? deg_src : deg_dst;
  int* rp = (blockIdx.x==0) ? rp_src : rp_dst;
  __shared__ int part[1024];
  int tid = threadIdx.x;
  const int per = (NN + 1023)/1024;   // 10
  int base = tid*per;
  int s = 0;
  for (int i=0;i<per;i++){ int idx=base+i; if (idx<NN) s += deg[idx]; }
  part[tid]=s; __syncthreads();
  for (int off=1; off<1024; off<<=1){
    int v = part[tid];
    int add = (tid>=off) ? part[tid-off] : 0;
    __syncthreads();
    part[tid] = v + add;
    __syncthreads();
  }
  int run = (tid==0) ? 0 : part[tid-1];
  for (int i=0;i<per;i++){ int idx=base+i; if (idx<NN){ rp[idx]=run; run += deg[idx]; } }
  if (tid==1023) rp[NN] = part[1023];
}

__global__ __launch_bounds__(256) void k_fill(const int* __restrict__ src, const int* __restrict__ dst,
                       const int* __restrict__ rp_src, const int* __restrict__ rp_dst,
                       int* fill_src, int* fill_dst, int* pos_src, int* dstp, int* srcd){
  int i = blockIdx.x*256 + threadIdx.x;
  if (i < NE){
    int s=src[i], d=dst[i];
    int p=rp_src[s]+atomicAdd(&fill_src[s],1); pos_src[i]=p; dstp[p]=d;
    int q=rp_dst[d]+atomicAdd(&fill_dst[d],1); srcd[q]=s;
  }
}

// ---------------- weight packs (edge MLP + We3 hi/lo A-frags), one dispatch ----------------
__global__ __launch_bounds__(256) void k_packall(const float* __restrict__ We1, const float* __restrict__ be1,
    const float* __restrict__ We2, const float* __restrict__ We3,
    unsigned short* __restrict__ W1p, unsigned short* __restrict__ W2p,
    unsigned short* __restrict__ W3h, unsigned short* __restrict__ W3l){
  int tid = threadIdx.x;
  if (blockIdx.x == 32){
    for (int idx=tid; idx<512; idx+=256){
      int j=idx>>6, l=idx&63, col=l&15, g=l>>4;
      int out = j*16+col;
      #pragma unroll
      for (int jj=0;jj<8;jj++){
        int k = g*8+jj;
        float v = (k<16) ? We1[k*128+out] : (k==16 ? be1[out] : 0.f);
        W1p[idx*8+jj] = f2bf(v);
      }
    }
    for (int idx=tid; idx<1024; idx+=256){
      int ft=idx>>6, l=idx&63, col=l&15, g=l>>4;
      int t=ft>>2, jo=ft&3;
      int out = jo*16+col;
      #pragma unroll
      for (int jj=0;jj<8;jj++){
        int k = t*32+g*8+jj;
        W2p[idx*8+jj] = f2bf(We2[k*64+out]);
      }
    }
  } else {
    int idx = blockIdx.x*256 + tid;   // [0, 8192)
    int jt = idx>>6, l = idx&63;
    int j = jt*16 + (l&15);
    int f0 = (l>>4)*8;
    int k = j>>5, o = j&31;
    #pragma unroll
    for (int jj=0;jj<8;jj++){
      float v = We3[(size_t)k*1024 + (size_t)(f0+jj)*32 + o];
      unsigned short h = f2bf(v);
      float r = v - bf2f(h);
      W3h[(size_t)idx*8+jj] = h;
      W3l[(size_t)idx*8+jj] = f2bf(r);
    }
  }
}

// ---------------- EdgeMLP via MFMA -> t2b (f16 k-pairs) in CSR-src order ----------------
__global__ __launch_bounds__(256) void k_edge_mlp2(const float* __restrict__ ea,
    const unsigned short* __restrict__ W1p, const unsigned short* __restrict__ W2p,
    const float* __restrict__ be2, const int* __restrict__ pos_src, unsigned* __restrict__ t2b){
  __shared__ unsigned short st1[4*2048];   // [wave][16 edges][128 k] bf16, XOR-swizzled
  int tid=threadIdx.x, wave=tid>>6, lane=tid&63;
  int c = lane&15, g = lane>>4;
  s8v w1f[8], w2f[16];
  #pragma unroll
  for (int j=0;j<8;j++)  w1f[j] = *(const s8v*)(W1p + (size_t)(j*64+lane)*8);
  #pragma unroll
  for (int q=0;q<16;q++) w2f[q] = *(const s8v*)(W2p + (size_t)(q*64+lane)*8);
  float be2v[16];
  #pragma unroll
  for (int jo=0;jo<4;jo++)
    #pragma unroll
    for (int r=0;r<4;r++) be2v[jo*4+r] = be2[jo*16+g*4+r];
  char* myld = (char*)(st1 + wave*2048);
  const f4v fzero = {0.f,0.f,0.f,0.f};

  for (int base = blockIdx.x*64; base < NE; base += gridDim.x*64){
    int e0 = base + wave*16;
    s8v eaf = {0,0,0,0,0,0,0,0};
    if (g < 2){
      const float* p = ea + (size_t)(e0+c)*16 + g*8;
      float4 a = *(const float4*)p;
      float4 b = *(const float4*)(p+4);
      eaf[0]=(short)f2bf(a.x); eaf[1]=(short)f2bf(a.y); eaf[2]=(short)f2bf(a.z); eaf[3]=(short)f2bf(a.w);
      eaf[4]=(short)f2bf(b.x); eaf[5]=(short)f2bf(b.y); eaf[6]=(short)f2bf(b.z); eaf[7]=(short)f2bf(b.w);
    } else if (g == 2){
      eaf[0] = (short)0x3f80;  // bf16(1.0) bias slot
    }
    f4v acc1[8];
    #pragma unroll
    for (int j=0;j<8;j++)
      acc1[j] = __builtin_amdgcn_mfma_f32_16x16x32_bf16(w1f[j], eaf, fzero, 0, 0, 0);
    #pragma unroll
    for (int j=0;j<8;j++){
      unsigned lo = (unsigned)f2bf(fmaxf(acc1[j][0],0.f)) | ((unsigned)f2bf(fmaxf(acc1[j][1],0.f))<<16);
      unsigned hi = (unsigned)f2bf(fmaxf(acc1[j][2],0.f)) | ((unsigned)f2bf(fmaxf(acc1[j][3],0.f))<<16);
      unsigned off = (unsigned)(c*256 + ((j*32 + g*8) ^ (c<<4)));
      *(uint2*)(myld + off) = make_uint2(lo, hi);
    }
    __syncthreads();
    f4v acc2[4];
    #pragma unroll
    for (int jo=0;jo<4;jo++) acc2[jo] = fzero;
    #pragma unroll
    for (int t=0;t<4;t++){
      unsigned off = (unsigned)(c*256 + ((t*64 + g*16) ^ (c<<4)));
      s8v b2 = *(const s8v*)(myld + off);
      #pragma unroll
      for (int jo=0;jo<4;jo++)
        acc2[jo] = __builtin_amdgcn_mfma_f32_16x16x32_bf16(w2f[t*4+jo], b2, acc2[jo], 0, 0, 0);
    }
    int pos = pos_src[e0+c];
    unsigned* orow = t2b + (size_t)pos*32;
    #pragma unroll
    for (int jo=0;jo<4;jo++){
      float v0 = fmaxf(acc2[jo][0] + be2v[jo*4+0], 0.f);
      float v1 = fmaxf(acc2[jo][1] + be2v[jo*4+1], 0.f);
      float v2 = fmaxf(acc2[jo][2] + be2v[jo*4+2], 0.f);
      float v3 = fmaxf(acc2[jo][3] + be2v[jo*4+3], 0.f);
      *(uint2*)(orow + jo*8 + g*2) = make_uint2(pkh(v0,v1), pkh(v2,v3));
    }
    __syncthreads();
  }
}

// ---------------- Y via MFMA (hi/lo) -> f16 k-pair layout, direct to global ----------------
// Yp[n*1024 + o*32 + ((kpg+(o>>1))&7)*4 + kr] = half2(Y[n,2kp*32+o], Y[n,(2kp+1)*32+o]), kp=kpg*4+kr
__global__ __launch_bounds__(256) void k_y5(const float* __restrict__ x,
    const unsigned short* __restrict__ W3h, const unsigned short* __restrict__ W3l,
    unsigned* __restrict__ Yp){
  int tid=threadIdx.x, w=tid>>6, l=tid&63;
  int c = l&15, g = l>>4;
  int tile = blockIdx.x*2 + (w>>1);
  if (tile >= 625) return;
  int jhalf = w&1;
  int n = tile*16 + c;
  const float* xr = x + (size_t)n*32 + g*8;
  float4 xa = *(const float4*)xr;
  float4 xc = *(const float4*)(xr+4);
  float xv[8] = {xa.x,xa.y,xa.z,xa.w,xc.x,xc.y,xc.z,xc.w};
  s8v bh, bl;
  #pragma unroll
  for (int jj=0;jj<8;jj++){
    unsigned short h = f2bf(xv[jj]);
    bh[jj] = (short)h;
    bl[jj] = (short)f2bf(xv[jj] - bf2f(h));
  }
  const f4v fz = {0.f,0.f,0.f,0.f};
  unsigned* Yrow = Yp + (size_t)n*1024;
  for (int grp=0; grp<4; grp++){
    int jt_g0 = jhalf*64 + grp*16;
    int kpg = jhalf*4 + grp;
    uint4 Q[2][4];
    #pragma unroll
    for (int a=0; a<4; a++){
      #pragma unroll
      for (int b=0; b<2; b++){
        int jt_lo = jt_g0 + 4*a + b;
        int jt_hi = jt_lo + 2;
        s8v AhL = *(const s8v*)(W3h + (size_t)(jt_lo*64 + l)*8);
        s8v AlL = *(const s8v*)(W3l + (size_t)(jt_lo*64 + l)*8);
        f4v aL = __builtin_amdgcn_mfma_f32_16x16x32_bf16(AhL, bl, fz, 0, 0, 0);
        aL = __builtin_amdgcn_mfma_f32_16x16x32_bf16(AlL, bh, aL, 0, 0, 0);
        aL = __builtin_amdgcn_mfma_f32_16x16x32_bf16(AhL, bh, aL, 0, 0, 0);
        s8v AhH = *(const s8v*)(W3h + (size_t)(jt_hi*64 + l)*8);
        s8v AlH = *(const s8v*)(W3l + (size_t)(jt_hi*64 + l)*8);
        f4v aH = __builtin_amdgcn_mfma_f32_16x16x32_bf16(AhH, bl, fz, 0, 0, 0);
        aH = __builtin_amdgcn_mfma_f32_16x16x32_bf16(AlH, bh, aH, 0, 0, 0);
        aH = __builtin_amdgcn_mfma_f32_16x16x32_bf16(AhH, bh, aH, 0, 0, 0);
        #pragma unroll
        for (int r=0;r<4;r++){
          unsigned pv = pkh(aL[r], aH[r]);
          if (a==0) Q[b][r].x = pv;
          else if (a==1) Q[b][r].y = pv;
          else if (a==2) Q[b][r].z = pv;
          else Q[b][r].w = pv;
        }
      }
    }
    #pragma unroll
    for (int b=0;b<2;b++)
      #pragma unroll
      for (int r=0;r<4;r++){
        int o = b*16 + g*4 + r;
        int slot = (kpg + (o>>1)) & 7;
        *(uint4*)(Yrow + o*32 + slot*4) = Q[b][r];
      }
  }
}

// ---------------- xb[n,o] = x@be3-fold ; agg-init = x@Wroot + bc1 ----------------
__global__ __launch_bounds__(256) void k_xbagg(const float* __restrict__ x,
    const float* __restrict__ be3, const float* __restrict__ Wroot, const float* __restrict__ bc1,
    float* __restrict__ xb, float* __restrict__ agg){
  __shared__ __align__(16) float sx[8][32];
  int oo = threadIdx.x & 31, nn = threadIdx.x >> 5;
  float wb[32], wr[32];
  #pragma unroll
  for (int f=0;f<32;f++){ wb[f]=be3[f*32+oo]; wr[f]=Wroot[f*32+oo]; }
  float bcv = bc1[oo];
  int per = (1250 + gridDim.x - 1)/gridDim.x;
  int g0 = blockIdx.x*per, g1 = min(g0+per, 1250);
  for (int gi=g0; gi<g1; gi++){
    int nb = gi*8;
    __syncthreads();
    sx[threadIdx.x>>5][threadIdx.x&31] = x[(size_t)nb*32 + threadIdx.x];
    __syncthreads();
    float a1=0.f, a2=0.f;
    #pragma unroll
    for (int f4=0;f4<8;f4++){
      float4 xvv = *(const float4*)(&sx[nn][f4*4]);
      a1 += xvv.x*wb[f4*4+0]+xvv.y*wb[f4*4+1]+xvv.z*wb[f4*4+2]+xvv.w*wb[f4*4+3];
      a2 += xvv.x*wr[f4*4+0]+xvv.y*wr[f4*4+1]+xvv.z*wr[f4*4+2]+xvv.w*wr[f4*4+3];
    }
    xb[(size_t)(nb+nn)*32+oo] = a1;
    agg[(size_t)(nb+nn)*32+oo] = a2 + bcv;
  }
}

// ---------------- msg+aggregate: agg[dst] += xb[src] + t2[e]·Yrow(src), f16 dot2 ----------------
__global__ __launch_bounds__(256) void k_msg3(const unsigned* __restrict__ Yp,
    const float* __restrict__ xb, const unsigned* __restrict__ t2b,
    const int* __restrict__ rp_src, const int* __restrict__ dstp,
    float* __restrict__ agg){
  __shared__ __align__(16) unsigned sY[4][1024];
  int tid=threadIdx.x, w=tid>>6, lane=tid&63;
  int es = lane>>4, l = lane&15;
  int gw = blockIdx.x*4 + w, stride = gridDim.x*4;
  for (int n=gw; n<NN; n+=stride){
    int beg=rp_src[n], end=rp_src[n+1];
    if (beg==end) continue;
    const unsigned* Yr = Yp + (size_t)n*1024;
    #pragma unroll
    for (int q=0;q<4;q++)
      *(uint4*)(&sY[w][q*256 + lane*4]) = *(const uint4*)(Yr + q*256 + lane*4);
    float2 xbv = *(const float2*)(xb + (size_t)n*32 + 2*l);
    __builtin_amdgcn_wave_barrier();
    for (int pb=beg; pb<end; pb+=4){
      const unsigned* trow = t2b + (size_t)(pb+es)*32;
      uint4 T[8];
      #pragma unroll
      for (int q=0;q<8;q++) T[q] = *(const uint4*)(trow + q*4);
      float acc0 = xbv.x, acc1 = xbv.y;
      #pragma unroll
      for (int kpg=0;kpg<8;kpg++){
        int slot4 = ((kpg + l)&7)*4;
        uint4 y0 = *(const uint4*)(&sY[w][(2*l  )*32 + slot4]);
        uint4 y1 = *(const uint4*)(&sY[w][(2*l+1)*32 + slot4]);
        acc0 = dot2h(T[kpg].x, y0.x, acc0);
        acc0 = dot2h(T[kpg].y, y0.y, acc0);
        acc0 = dot2h(T[kpg].z, y0.z, acc0);
        acc0 = dot2h(T[kpg].w, y0.w, acc0);
        acc1 = dot2h(T[kpg].x, y1.x, acc1);
        acc1 = dot2h(T[kpg].y, y1.y, acc1);
        acc1 = dot2h(T[kpg].z, y1.z, acc1);
        acc1 = dot2h(T[kpg].w, y1.w, acc1);
      }
      int p = pb + es;
      if (p < end){
        int d = dstp[p];
        float* ap = agg + (size_t)d*32 + 2*l;
        unsafeAtomicAdd(ap,   acc0);
        unsafeAtomicAdd(ap+1, acc1);
      }
    }
  }
}

// ---------------- column stats (sum, sumsq); stats pre-zeroed ----------------
__global__ __launch_bounds__(256) void k_stats(const float* __restrict__ buf, int nrows, int ncols,
                                               float* __restrict__ stats){
  int tid = threadIdx.x;
  int c  = tid % ncols;
  int r0 = tid / ncols;
  int rp = 256 / ncols;
  float s1=0.f, s2=0.f;
  for (long long base=(long long)blockIdx.x*rp; base<nrows; base+=(long long)gridDim.x*rp){
    int r = (int)base + r0;
    if (r < nrows){
      float v = buf[(size_t)r*ncols + c];
      s1 += v; s2 += v*v;
    }
  }
  __shared__ float A[256], B[256];
  A[tid]=s1; B[tid]=s2; __syncthreads();
  if (tid < ncols){
    float t1=0.f, t2=0.f;
    for (int gg=0; gg<256/ncols; gg++){ t1 += A[gg*ncols+tid]; t2 += B[gg*ncols+tid]; }
    atomicAdd(&stats[tid], t1);
    atomicAdd(&stats[ncols+tid], t2);
  }
}

// ---------------- GAT linear: in=relu(bn(raw)); hWh=f16(in@W); sc_s,sc_d ----------------
template<int FIN, int FOUT>
__global__ __launch_bounds__(256) void k_gat_linear(const float* __restrict__ raw,
    const float* __restrict__ stats, const float* __restrict__ W,
    const float* __restrict__ avs, const float* __restrict__ avd,
    unsigned short* __restrict__ hWh, float* __restrict__ sc_s, float* __restrict__ sc_d){
  __shared__ float sW[FIN*FOUT];
  __shared__ float sA[FOUT], sD[FOUT];
  __shared__ float sScale[FIN], sShift[FIN];
  __shared__ float sIn[4][FIN];
  int tid = threadIdx.x;
  for (int i=tid;i<FIN*FOUT;i+=256) sW[i]=W[i];
  if (tid<FOUT){ sA[tid]=avs[tid]; sD[tid]=avd[tid]; }
  if (tid<FIN){
    float m = stats[tid]*(1.f/NN);
    float v = stats[FIN+tid]*(1.f/NN) - m*m;
    float s = rsqrtf(v + 1e-5f);
    sScale[tid]=s; sShift[tid]=-m*s;
  }
  __syncthreads();
  int wave=tid>>6, lane=tid&63;
  for (int nb = blockIdx.x*4; nb < NN; nb += gridDim.x*4){
    int n = nb + wave;
    bool act = n < NN;
    if (act){
      for (int ff=lane; ff<FIN; ff+=64){
        float vv = raw[(size_t)n*FIN+ff]*sScale[ff]+sShift[ff];
        sIn[wave][ff] = fmaxf(vv, 0.f);
      }
    }
    __syncthreads();
    if (act){
      float out0=0.f, out1=0.f;
      #pragma unroll
      for (int ff=0; ff<FIN; ff++){
        float xv = sIn[wave][ff];
        out0 += xv*sW[ff*FOUT+lane];
        if constexpr (FOUT > 64) out1 += xv*sW[ff*FOUT+lane+64];
      }
      hWh[(size_t)n*FOUT + lane] = f2h(out0);
      float ps = out0*sA[lane], pd = out0*sD[lane];
      if constexpr (FOUT > 64){
        hWh[(size_t)n*FOUT + lane + 64] = f2h(out1);
        ps += out1*sA[lane+64]; pd += out1*sD[lane+64];
      }
      #pragma unroll
      for (int off=32;off>0;off>>=1){ ps += __shfl_down(ps,off); pd += __shfl_down(pd,off); }
      if (lane==0){ sc_s[n]=ps; sc_d[n]=pd; }
    }
    __syncthreads();
  }
}

// ---------------- GAT attention: online softmax, shfl broadcast, f16 gathers, fused stats ----------------
template<int F>
__global__ __launch_bounds__(256) void k_gat_attn3(const unsigned short* __restrict__ hWh,
    const float* __restrict__ sc_s, const float* __restrict__ sc_d,
    const int* __restrict__ rp_dst, const int* __restrict__ srcd,
    const float* __restrict__ bias, float* __restrict__ outraw, float* __restrict__ stats){
  int tid=threadIdx.x, w=tid>>6, lane=tid&63;
  int gw = blockIdx.x*4 + w, stride = gridDim.x*4;
  float s1a=0.f, s2a=0.f, s1b=0.f, s2b=0.f;
  for (int n=gw; n<NN; n+=stride){
    int beg=rp_dst[n], end=rp_dst[n+1];
    float scd = sc_d[n];
    float M=-3e38f, S=0.f, acc0=0.f, acc1=0.f;
    for (int base=beg; base<end; base+=64){
      int nb = min(64, end-base);
      int si=0; float sc=-3e38f;
      if (lane<nb){ si = srcd[base+lane]; sc = lrelu(sc_s[si]+scd); }
      float cm=sc;
      #pragma unroll
      for (int off=32;off>0;off>>=1) cm = fmaxf(cm, __shfl_xor(cm,off));
      float Mn = fmaxf(M, cm);
      float p = (lane<nb) ? __expf(sc-Mn) : 0.f;
      float ps=p;
      #pragma unroll
      for (int off=32;off>0;off>>=1) ps += __shfl_xor(ps,off);
      float scale = __expf(M-Mn);
      S = S*scale + ps;
      acc0*=scale; acc1*=scale;
      for (int jj=0;jj<nb;jj++){
        float pj = __shfl(p, jj);
        int   sj = __shfl(si, jj);
        if constexpr (F==128){
          unsigned u = *(const unsigned*)(hWh + (size_t)sj*128 + 2*lane);
          acc0 += pj*h2f((unsigned short)(u&0xffffu));
          acc1 += pj*h2f((unsigned short)(u>>16));
        } else {
          acc0 += pj*h2f(hWh[(size_t)sj*64+lane]);
        }
      }
      M = Mn;
    }
    float sself = lrelu(sc_s[n]+scd);
    float Mn = fmaxf(M, sself);
    float scale = __expf(M-Mn);
    float pself = __expf(sself-Mn);
    S = S*scale + pself;
    acc0*=scale; acc1*=scale;
    float inv = 1.f/(S+1e-16f);
    if constexpr (F==128){
      unsigned u = *(const unsigned*)(hWh + (size_t)n*128 + 2*lane);
      acc0 += pself*h2f((unsigned short)(u&0xffffu));
      acc1 += pself*h2f((unsigned short)(u>>16));
      float ox = acc0*inv + bias[2*lane];
      float oy = acc1*inv + bias[2*lane+1];
      *(float2*)(outraw + (size_t)n*128 + 2*lane) = make_float2(ox, oy);
      s1a += ox; s2a += ox*ox; s1b += oy; s2b += oy*oy;
    } else {
      acc0 += pself*h2f(hWh[(size_t)n*64+lane]);
      float ox = acc0*inv + bias[lane];
      outraw[(size_t)n*64+lane] = ox;
      s1a += ox; s2a += ox*ox;
    }
  }
  // block-level stats reduce + atomics
  __shared__ float sred[256];
  sred[tid]=s1a; __syncthreads();
  if (tid<64){ float v=sred[tid]+sred[tid+64]+sred[tid+128]+sred[tid+192];
               atomicAdd(&stats[(F==128)?2*tid:tid], v); }
  __syncthreads();
  sred[tid]=s2a; __syncthreads();
  if (tid<64){ float v=sred[tid]+sred[tid+64]+sred[tid+128]+sred[tid+192];
               atomicAdd(&stats[F + ((F==128)?2*tid:tid)], v); }
  __syncthreads();
  if constexpr (F==128){
    sred[tid]=s1b; __syncthreads();
    if (tid<64){ float v=sred[tid]+sred[tid+64]+sred[tid+128]+sred[tid+192];
                 atomicAdd(&stats[2*tid+1], v); }
    __syncthreads();
    sred[tid]=s2b; __syncthreads();
    if (tid<64){ float v=sred[tid]+sred[tid+64]+sred[tid+128]+sred[tid+192];
                 atomicAdd(&stats[F + 2*tid+1], v); }
  }
}

// ---------------- mean pool with bn+relu on read ----------------
__global__ __launch_bounds__(256) void k_pool(const float* __restrict__ h2raw,
    const float* __restrict__ stats, const int* __restrict__ starts,
    float* __restrict__ g){
  __shared__ float sc[128], sh[128];
  __shared__ float red[256];
  int b=blockIdx.x, t=threadIdx.x;
  if (t<128){
    float m = stats[t]*(1.f/NN);
    float v = stats[128+t]*(1.f/NN) - m*m;
    float s = rsqrtf(v+1e-5f);
    sc[t]=s; sh[t]=-m*s;
  }
  __syncthreads();
  int s0=starts[b], s1=starts[b+1];
  int f=t&127, half=t>>7;
  float acc=0.f;
  for (int n=s0+half;n<s1;n+=2){
    float v = h2raw[(size_t)n*128+f]*sc[f]+sh[f];
    acc += fmaxf(v,0.f);
  }
  red[t]=acc; __syncthreads();
  if (half==0){
    int cnt = s1-s0;
    g[b*128+f] = (red[f]+red[128+f]) / fmaxf((float)cnt, 1.f);
  }
}

// ---------------- FC head (stats fused via atomics) ----------------
__global__ __launch_bounds__(256) void k_head1(const float* __restrict__ g,
    const float* __restrict__ Wf1, const float* __restrict__ bf1, float* __restrict__ g1,
    float* __restrict__ statsH1){
  __shared__ float sg[128];
  int r=blockIdx.x, t=threadIdx.x;
  if (t<128) sg[t]=g[r*128+t];
  __syncthreads();
  float acc=bf1[t];
  #pragma unroll 4
  for (int k=0;k<128;k++) acc += sg[k]*Wf1[k*256+t];
  g1[r*256+t]=acc;
  atomicAdd(&statsH1[t], acc);
  atomicAdd(&statsH1[256+t], acc*acc);
}

__global__ __launch_bounds__(256) void k_head2(const float* __restrict__ g1,
    const float* __restrict__ stats, const float* __restrict__ Wf2,
    const float* __restrict__ bf2, float* __restrict__ g2, float* __restrict__ statsH2){
  __shared__ float sin_[256];
  int r=blockIdx.x, t=threadIdx.x;
  float m = stats[t]*(1.f/NGB);
  float v = stats[256+t]*(1.f/NGB) - m*m;
  float val = (g1[r*256+t]-m)*rsqrtf(v+1e-5f);
  sin_[t]=fmaxf(val,0.f);
  __syncthreads();
  if (t<128){
    float acc=bf2[t];
    #pragma unroll 4
    for (int k=0;k<256;k++) acc += sin_[k]*Wf2[k*128+t];
    g2[r*128+t]=acc;
    atomicAdd(&statsH2[t], acc);
    atomicAdd(&statsH2[128+t], acc*acc);
  }
}

__global__ __launch_bounds__(256) void k_head3(const float* __restrict__ g2,
    const float* __restrict__ stats, const float* __restrict__ Wf3,
    const float* __restrict__ bf3, float* __restrict__ out){
  __shared__ float sin_[128];
  int r=blockIdx.x, t=threadIdx.x;
  if (t<128){
    float m = stats[t]*(1.f/NGB);
    float v = stats[128+t]*(1.f/NGB) - m*m;
    float val = (g2[r*128+t]-m)*rsqrtf(v+1e-5f);
    sin_[t]=fmaxf(val,0.f);
  }
  __syncthreads();
  if (t<64){
    float acc=bf3[t];
    #pragma unroll 4
    for (int k=0;k<128;k++) acc += sin_[k]*Wf3[k*64+t];
    out[r*64+t]=acc;
  }
}

extern "C" void kernel_launch(void* const* d_in, const int* in_sizes, int n_in,
                              void* d_out, int out_size, void* d_ws, size_t ws_size,
                              hipStream_t stream){
  const float* x    = (const float*)d_in[0];
  const int*   ei   = (const int*)d_in[1];
  const float* ea   = (const float*)d_in[2];
  const int*   batch= (const int*)d_in[3];
  const float* We1=(const float*)d_in[4];  const float* be1=(const float*)d_in[5];
  const float* We2=(const float*)d_in[6];  const float* be2=(const float*)d_in[7];
  const float* We3=(const float*)d_in[8];  const float* be3=(const float*)d_in[9];
  const float* Wroot=(const float*)d_in[10]; const float* bc1=(const float*)d_in[11];
  const float* Wg1=(const float*)d_in[12]; const float* as1=(const float*)d_in[13];
  const float* ad1=(const float*)d_in[14]; const float* bg1=(const float*)d_in[15];
  const float* Wg2=(const float*)d_in[16]; const float* as2=(const float*)d_in[17];
  const float* ad2=(const float*)d_in[18]; const float* bg2=(const float*)d_in[19];
  const float* Wf1=(const float*)d_in[20]; const float* bf1=(const float*)d_in[21];
  const float* Wf2=(const float*)d_in[22]; const float* bf2=(const float*)d_in[23];
  const float* Wf3=(const float*)d_in[24]; const float* bf3=(const float*)d_in[25];
  (void)in_sizes; (void)n_in; (void)out_size; (void)ws_size;
  float* out = (float*)d_out;
  char* ws = (char*)d_ws;
  const int* srcA = ei;
  const int* dstA = ei + NE;

  size_t off = 0;
  auto take = [&](size_t bytes)->size_t{ size_t r = off; off += (bytes + 255) & ~(size_t)255; return r; };
  // zero region
  size_t o_deg_src = take(NN*4), o_deg_dst = take(NN*4);
  size_t o_fill_src = take(NN*4), o_fill_dst = take(NN*4);
  size_t o_stats0 = take(2*32*4), o_stats1 = take(2*64*4), o_stats2 = take(2*128*4);
  size_t o_statsH1 = take(2*256*4), o_statsH2 = take(2*128*4);
  size_t zero_bytes = off;
  // rest
  size_t o_rp_src = take((NN+1)*4), o_rp_dst = take((NN+1)*4);
  size_t o_pos_src = take((size_t)NE*4);
  size_t o_dstp = take((size_t)NE*4);
  size_t o_srcd = take((size_t)NE*4);
  size_t o_starts = take((NGB+1)*4);
  size_t o_W1p = take(4096*2);
  size_t o_W2p = take(8192*2);
  size_t o_W3h = take((size_t)128*64*8*2);
  size_t o_W3l = take((size_t)128*64*8*2);
  size_t o_t2b = take((size_t)(NE+8)*32*4);        // f16 k-pairs
  size_t o_Yp  = take((size_t)NN*1024*4);          // f16 k-pairs
  size_t o_xb  = take((size_t)NN*32*4);
  size_t o_agg = take((size_t)NN*32*4);
  size_t o_hW1 = take((size_t)NN*64*2);
  size_t o_scs1 = take(NN*4), o_scd1 = take(NN*4);
  size_t o_h1  = take((size_t)NN*64*4);
  size_t o_hW2 = take((size_t)NN*128*2);
  size_t o_scs2 = take(NN*4), o_scd2 = take(NN*4);
  size_t o_h2  = take((size_t)NN*128*4);
  size_t o_g   = take(NGB*128*4);
  size_t o_g1  = take(NGB*256*4);
  size_t o_g2  = take(NGB*128*4);

  #define WF(o) ((float*)(ws + (o)))
  #define WI(o) ((int*)(ws + (o)))
  #define WU(o) ((unsigned short*)(ws + (o)))
  #define WW(o) ((unsigned*)(ws + (o)))

  (void)hipMemsetAsync(ws, 0, zero_bytes, stream);
  k_deg_bounds<<<625,256,0,stream>>>(srcA,dstA,batch,WI(o_deg_src),WI(o_deg_dst),WI(o_starts));
  k_scan<<<2,1024,0,stream>>>(WI(o_deg_src),WI(o_deg_dst),WI(o_rp_src),WI(o_rp_dst));
  k_fill<<<625,256,0,stream>>>(srcA,dstA,WI(o_rp_src),WI(o_rp_dst),
                               WI(o_fill_src),WI(o_fill_dst),
                               WI(o_pos_src),WI(o_dstp),WI(o_srcd));
  k_packall<<<33,256,0,stream>>>(We1,be1,We2,We3,WU(o_W1p),WU(o_W2p),WU(o_W3h),WU(o_W3l));
  k_edge_mlp2<<<500,256,0,stream>>>(ea,WU(o_W1p),WU(o_W2p),be2,WI(o_pos_src),WW(o_t2b));
  k_y5<<<313,256,0,stream>>>(x,WU(o_W3h),WU(o_W3l),WW(o_Yp));
  k_xbagg<<<256,256,0,stream>>>(x,be3,Wroot,bc1,WF(o_xb),WF(o_agg));
  k_msg3<<<1250,256,0,stream>>>(WW(o_Yp),WF(o_xb),WW(o_t2b),WI(o_rp_src),WI(o_dstp),WF(o_agg));

  k_stats<<<64,256,0,stream>>>(WF(o_agg),NN,32,WF(o_stats0));
  k_gat_linear<32,64><<<640,256,0,stream>>>(WF(o_agg),WF(o_stats0),Wg1,as1,ad1,
                                            WU(o_hW1),WF(o_scs1),WF(o_scd1));
  k_gat_attn3<64><<<640,256,0,stream>>>(WU(o_hW1),WF(o_scs1),WF(o_scd1),
                                        WI(o_rp_dst),WI(o_srcd),bg1,WF(o_h1),WF(o_stats1));
  k_gat_linear<64,128><<<640,256,0,stream>>>(WF(o_h1),WF(o_stats1),Wg2,as2,ad2,
                                             WU(o_hW2),WF(o_scs2),WF(o_scd2));
  k_gat_attn3<128><<<640,256,0,stream>>>(WU(o_hW2),WF(o_scs2),WF(o_scd2),
                                         WI(o_rp_dst),WI(o_srcd),bg2,WF(o_h2),WF(o_stats2));

  k_pool<<<NGB,256,0,stream>>>(WF(o_h2),WF(o_stats2),WI(o_starts),WF(o_g));
  k_head1<<<NGB,256,0,stream>>>(WF(o_g),Wf1,bf1,WF(o_g1),WF(o_statsH1));
  k_head2<<<NGB,256,0,stream>>>(WF(o_g1),WF(o_statsH1),Wf2,bf2,WF(o_g2),WF(o_statsH2));
  k_head3<<<NGB,256,0,stream>>>(WF(o_g2),WF(o_statsH2),Wf3,bf3,out);
}